// Round 6
// baseline (2639.555 us; speedup 1.0000x reference)
//
#include <hip/hip_runtime.h>

typedef unsigned short u16;
typedef __bf16 bf16x8 __attribute__((ext_vector_type(8)));
typedef float f32x4 __attribute__((ext_vector_type(4)));

#define DEVI __device__ __forceinline__

DEVI u16 f2b(float f) {
  union { float f; unsigned u; } c; c.f = f;
  unsigned r = c.u + 0x7FFFu + ((c.u >> 16) & 1u);
  return (u16)(r >> 16);
}

DEVI float sigm(float x) { return 1.f / (1.f + __expf(-x)); }
DEVI float tanhfast(float x) {
  x = fminf(fmaxf(x, -15.f), 15.f);
  float e = __expf(2.f * x);
  return (e - 1.f) / (e + 1.f);
}

DEVI void async16(const void* g, void* l) {
  __builtin_amdgcn_global_load_lds((const __attribute__((address_space(1))) void*)g,
                                   (__attribute__((address_space(3))) void*)l, 16, 0, 0);
}

// LLC-coherent (cross-XCD) bypass ops. Caller must s_waitcnt vmcnt before
// consuming load results (rule 18).
DEVI float ldf_p(const float* p) { float r; asm volatile("global_load_dword %0, %1, off"         : "=v"(r) : "v"(p) : "memory"); return r; }
DEVI float ldf_g(const float* p) { float r; asm volatile("global_load_dword %0, %1, off sc0 sc1" : "=v"(r) : "v"(p) : "memory"); return r; }
DEVI f32x4 ld16_g(const u16* p)  { f32x4 r; asm volatile("global_load_dwordx4 %0, %1, off sc0 sc1" : "=v"(r) : "v"(p) : "memory"); return r; }
DEVI void  st32_g(unsigned* p, unsigned v) { asm volatile("global_store_dword %0, %1, off sc0 sc1" :: "v"(p), "v"(v) : "memory"); }
DEVI void  stf_g(float* p, float v)        { asm volatile("global_store_dword %0, %1, off sc0 sc1" :: "v"(p), "v"(v) : "memory"); }

#define VM0 asm volatile("s_waitcnt vmcnt(0)" ::: "memory")
#define LK0 asm volatile("s_waitcnt lgkmcnt(0)" ::: "memory")
#define SBAR __builtin_amdgcn_sched_barrier(0)
#define BAR __builtin_amdgcn_s_barrier()

// ---------------- cast / pad fp32 -> bf16 ----------------
__global__ __launch_bounds__(256) void k_castpad(const float* __restrict__ src, u16* __restrict__ dst,
                                                 int srows, int scols, int drows, int dcols) {
  size_t n = (size_t)drows * dcols;
  for (size_t i = blockIdx.x * 256 + threadIdx.x; i < n; i += (size_t)gridDim.x * 256) {
    int r = (int)(i / dcols), c = (int)(i % dcols);
    float v = (r < srows && c < scols) ? src[(size_t)r * scols + c] : 0.f;
    dst[i] = f2b(v);
  }
}

// ---------------- embedding + time concat -> x0 bf16 [8192][288] ----------------
__global__ __launch_bounds__(256) void k_embed(const int* __restrict__ loc, const float* __restrict__ times,
                                               const float* __restrict__ emb, u16* __restrict__ x0) {
  int m = blockIdx.x * 4 + (threadIdx.x >> 6);  // m = t*32 + b
  int s = threadIdx.x & 63;
  int b = m & 31, t = m >> 5;
  int li = loc[b * 256 + t];
  const float4* er = (const float4*)(emb + (size_t)li * 256);
  u16* xr = x0 + (size_t)m * 288;
  float4 v = er[s];
  ushort4 u;
  u.x = f2b(v.x); u.y = f2b(v.y); u.z = f2b(v.z); u.w = f2b(v.w);
  *(ushort4*)(xr + s * 4) = u;
  if (s == 0) xr[256] = f2b(times[b * 256 + t]);
  else if (s <= 31) xr[256 + s] = 0;
}

// ---------------- init h seed (bf16) from traj_emb[labels] ----------------
__global__ __launch_bounds__(256) void k_hinit(const float* __restrict__ traj, const int* __restrict__ labels,
                                               u16* __restrict__ dst, int layer) {
  int idx = blockIdx.x * 256 + threadIdx.x;
  if (idx < 16384) {
    int fidx = layer * 16384 + idx;
    dst[idx] = f2b(traj[(size_t)labels[fidx >> 10] * 1024 + (fidx & 1023)]);
  }
}

// ---------------- seed mask[0] = all 32 blocks "done" ----------------
__global__ __launch_bounds__(64) void k_maskinit(unsigned* __restrict__ msk) {
  if (threadIdx.x == 0) msk[0] = 0xFFFFFFFFu;
}

// ---------------- bf16 MFMA GEMM: C[M,N] = A[M,K] * Bw[N,K]^T (+bias) ----------------
template <int MODE>
__global__ __launch_bounds__(256) void k_gemm(const u16* __restrict__ A, const u16* __restrict__ Bw,
                                              const float* __restrict__ bias, float* __restrict__ C,
                                              int N, int K, float* __restrict__ tptr) {
  __shared__ __align__(16) u16 As[128 * 32];
  __shared__ __align__(16) u16 Bs[128 * 32];
  const int tid = threadIdx.x;
  const int lane = tid & 63, wid = tid >> 6;
  const int tn = blockIdx.x, tm = blockIdx.y;
  const int wm = wid >> 1, wn = wid & 1;

  f32x4 acc[4][4] = {};

  const int r0 = tid >> 2;
  const int cb0 = (tid * 16) & 63;

  for (int k0 = 0; k0 < K; k0 += 32) {
    __syncthreads();
#pragma unroll
    for (int p = 0; p < 2; ++p) {
      int row = r0 + p * 64;
      const u16* ga = A + (size_t)(tm * 128 + row) * K + k0 + (cb0 >> 1);
      async16(ga, (void*)(As + wid * 512 + p * 2048));
      const u16* gb = Bw + (size_t)(tn * 128 + row) * K + k0 + (cb0 >> 1);
      async16(gb, (void*)(Bs + wid * 512 + p * 2048));
    }
    asm volatile("s_waitcnt vmcnt(0)" ::: "memory");
    __syncthreads();
    bf16x8 af[4], bf[4];
#pragma unroll
    for (int i = 0; i < 4; ++i) {
      af[i] = *reinterpret_cast<const bf16x8*>(As + (wm * 64 + i * 16 + (lane & 15)) * 32 + ((lane >> 4) * 8));
      bf[i] = *reinterpret_cast<const bf16x8*>(Bs + (wn * 64 + i * 16 + (lane & 15)) * 32 + ((lane >> 4) * 8));
    }
#pragma unroll
    for (int i = 0; i < 4; ++i)
#pragma unroll
      for (int j = 0; j < 4; ++j)
        acc[i][j] = __builtin_amdgcn_mfma_f32_16x16x32_bf16(af[i], bf[j], acc[i][j], 0, 0, 0);
  }

  const int row0 = tm * 128 + wm * 64;
  const int col0 = tn * 128 + wn * 64;
#pragma unroll
  for (int i = 0; i < 4; ++i)
#pragma unroll
    for (int j = 0; j < 4; ++j)
#pragma unroll
      for (int r = 0; r < 4; ++r) {
        int row = row0 + i * 16 + ((lane >> 4) * 4) + r;
        int col = col0 + j * 16 + (lane & 15);
        float v = acc[i][j][r];
        if (MODE == 0) {
          C[(size_t)row * N + col] = v + bias[col];
        } else {
          int orow = ((row & 31) << 8) + (row >> 5);  // b*256 + t
          if (col < 10000) C[(size_t)orow * 10000 + col] = v + bias[col];
          else if (col == 10000) tptr[orow] = sigm(v + bias[col]);
        }
      }
}

// ---------------- merged persistent 2-layer GRU scan, 32 blocks ----------------
// Block blk owns h0-cols [blk*16..+15] AND h1-cols [blk*16..+15]. Interval s:
//   h0(s) = GRU0(h0(s-1), xg0(s))                 [s<=255]
//   X1(s-1) = h0(s-1) @ w_ih1^T (48 gate-cols)     [1<=s<=256] -> x1x ring(4)
//   h1(s-3) = GRU1(h1(s-4), X1(s-3))               [s>=3]      -> h1seq
// Sync: ONE bitmask dword per interval (128B stride). Publisher: one
// fetch_or per block. Poller: wave 7 only, all lanes same dword, s_sleep
// backoff. All weights LDS-resident (3x48KB, XOR-swizzled). Gate inputs for
// both layers register-prefetched one interval ahead.
// LDS: 3*49152 weights + 12288 smD = 159744 B  (r5 bug: smD needs [4][3][256],
// 12288 B — h1 quadrants 6..11 were beyond the 153600 allocation; OOB DS
// writes are dropped -> h1 lost its w_hh1 term -> absmax 0.3125).
__global__ __launch_bounds__(512, 2)
void k_scan5(const float* __restrict__ xg0,
             const u16* __restrict__ whh0, const float* __restrict__ bhh0,
             const u16* __restrict__ wih1, const float* __restrict__ bih1,
             const u16* __restrict__ whh1, const float* __restrict__ bhh1,
             const float* __restrict__ traj, const int* __restrict__ labels,
             u16* __restrict__ h0x, u16* __restrict__ h1x, float* __restrict__ x1x,
             u16* __restrict__ h1seq, unsigned* __restrict__ msk)
{
  extern __shared__ __align__(16) char dynlds[];
  float* smD = (float*)(dynlds + 147456);  // [2 layers][2 mt][3 nt][16][16] = 12288B

  const int tid = threadIdx.x, blk = blockIdx.x;
  const int lane = tid & 63, wid = tid >> 6;
  const int eb = tid >> 4, ejj = tid & 15;
  const int jg = (blk << 4) + ejj;

  // ---- LDS preload: whh0 / wih1 / whh1 block-slices [48][512], XOR-swizzled ----
#pragma unroll
  for (int m = 0; m < 3; ++m) {
    const u16* srcm = (m == 0) ? whh0 : (m == 1) ? wih1 : whh1;
    char* dst = dynlds + m * 49152;
    for (int c = tid; c < 3072; c += 512) {
      int row = c >> 6, o16 = c & 63;
      int grow = (row >> 4) * 512 + (blk << 4) + (row & 15);
      const float4* src = (const float4*)(srcm + (size_t)grow * 512 + o16 * 8);
      int byte = (row << 10) + ((o16 * 16) ^ ((row & 7) << 4));
      *(float4*)(dst + byte) = *src;
    }
  }

  float h0_own, h1_own;
  {
    int f0 = eb * 512 + jg;
    h0_own = traj[(size_t)labels[f0 >> 10] * 1024 + (f0 & 1023)];
    int f1 = 16384 + eb * 512 + jg;
    h1_own = traj[(size_t)labels[f1 >> 10] * 1024 + (f1 & 1023)];
  }
  const float b0r = bhh0[jg], b0z = bhh0[512 + jg], b0n = bhh0[1024 + jg];
  const float b1r = bhh1[jg], b1z = bhh1[512 + jg], b1n = bhh1[1024 + jg];

  const int mt = (wid < 6) ? wid / 3 : 0, nt = (wid < 6) ? wid % 3 : 0;
  float bX = 0.f;
  if (wid < 6) bX = bih1[nt * 512 + (blk << 4) + (lane & 15)];

  __syncthreads();

  // gate prefetch registers (interval s values)
  float gxr = 0.f, gxz = 0.f, gxn = 0.f;  // layer0 x-gates xg0(s)
  float g1r = 0.f, g1z = 0.f, g1n = 0.f;  // layer1 x-gates X1(s-3)
  {
    const float* q = xg0 + (size_t)eb * 1536 + jg;
    gxr = ldf_p(q); gxz = ldf_p(q + 512); gxn = ldf_p(q + 1024);
  }

  for (int s = 0; s <= 258; ++s) {
    const int rp0 = (s + 1) & 1;  // h0(s-1) parity
    const int wp0 = s & 1;        // h0(s) parity
    const int rp1 = s & 1;        // h1(s-4) parity
    const int wp1 = (s + 1) & 1;  // h1(s-3) parity

    if (wid == 7) {
      const unsigned* mp = msk + (size_t)s * 32;
      while (__hip_atomic_load(mp, __ATOMIC_RELAXED, __HIP_MEMORY_SCOPE_AGENT) != 0xFFFFFFFFu)
        __builtin_amdgcn_s_sleep(1);
    }
    BAR;  // C: all interval-(s-1) data certified at LLC

    if (wid < 6) {
      const int col = lane & 15, rb = (lane >> 4) << 2;
      f32x4 afrA[16], afrB[16];
      if (s <= 256) {
        const u16* hs = h0x + (rp0 << 14) + ((mt * 16 + col) << 9) + ((lane >> 4) * 8);
#pragma unroll
        for (int ks = 0; ks < 16; ++ks) afrA[ks] = ld16_g(hs + ks * 32);
      }
      if (s >= 3) {
        const u16* hs = h1x + (rp1 << 14) + ((mt * 16 + col) << 9) + ((lane >> 4) * 8);
#pragma unroll
        for (int ks = 0; ks < 16; ++ks) afrB[ks] = ld16_g(hs + ks * 32);
      }
      VM0; SBAR;
      const int cb = (lane >> 4) << 4;
      const int swz = ((col & 7) << 4);
      const int rowoff = (nt * 16 + col) << 10;
      // h0-MFMA (w_hh0, LDS matrix 0)
      if (s <= 255) {
        f32x4 a0 = {0.f, 0.f, 0.f, 0.f}, a1 = {0.f, 0.f, 0.f, 0.f};
#pragma unroll
        for (int ks = 0; ks < 8; ++ks) {
          bf16x8 w0 = *(const bf16x8*)(dynlds + rowoff + (((2 * ks) * 64 + cb) ^ swz));
          bf16x8 w1 = *(const bf16x8*)(dynlds + rowoff + (((2 * ks + 1) * 64 + cb) ^ swz));
          a0 = __builtin_amdgcn_mfma_f32_16x16x32_bf16(__builtin_bit_cast(bf16x8, afrA[2 * ks]),     w0, a0, 0, 0, 0);
          a1 = __builtin_amdgcn_mfma_f32_16x16x32_bf16(__builtin_bit_cast(bf16x8, afrA[2 * ks + 1]), w1, a1, 0, 0, 0);
        }
#pragma unroll
        for (int r = 0; r < 4; ++r)
          smD[((0 + mt) * 3 + nt) * 256 + (rb + r) * 16 + col] = a0[r] + a1[r];
      }
      // X1-MFMA (w_ih1, LDS matrix 1) + early write-through stores
      if (s >= 1 && s <= 256) {
        f32x4 c0 = {0.f, 0.f, 0.f, 0.f}, c1 = {0.f, 0.f, 0.f, 0.f};
#pragma unroll
        for (int ks = 0; ks < 8; ++ks) {
          bf16x8 w0 = *(const bf16x8*)(dynlds + 49152 + rowoff + (((2 * ks) * 64 + cb) ^ swz));
          bf16x8 w1 = *(const bf16x8*)(dynlds + 49152 + rowoff + (((2 * ks + 1) * 64 + cb) ^ swz));
          c0 = __builtin_amdgcn_mfma_f32_16x16x32_bf16(__builtin_bit_cast(bf16x8, afrA[2 * ks]),     w0, c0, 0, 0, 0);
          c1 = __builtin_amdgcn_mfma_f32_16x16x32_bf16(__builtin_bit_cast(bf16x8, afrA[2 * ks + 1]), w1, c1, 0, 0, 0);
        }
        float* xp = x1x + (size_t)((s - 1) & 3) * 49152;
#pragma unroll
        for (int r = 0; r < 4; ++r) {
          int ebr = mt * 16 + rb + r;
          stf_g(xp + ((ebr * 3 + nt) << 9) + (blk << 4) + col, c0[r] + c1[r] + bX);
        }
      }
      // h1-MFMA (w_hh1, LDS matrix 2)
      if (s >= 3) {
        f32x4 d0 = {0.f, 0.f, 0.f, 0.f}, d1 = {0.f, 0.f, 0.f, 0.f};
#pragma unroll
        for (int ks = 0; ks < 8; ++ks) {
          bf16x8 w0 = *(const bf16x8*)(dynlds + 98304 + rowoff + (((2 * ks) * 64 + cb) ^ swz));
          bf16x8 w1 = *(const bf16x8*)(dynlds + 98304 + rowoff + (((2 * ks + 1) * 64 + cb) ^ swz));
          d0 = __builtin_amdgcn_mfma_f32_16x16x32_bf16(__builtin_bit_cast(bf16x8, afrB[2 * ks]),     w0, d0, 0, 0, 0);
          d1 = __builtin_amdgcn_mfma_f32_16x16x32_bf16(__builtin_bit_cast(bf16x8, afrB[2 * ks + 1]), w1, d1, 0, 0, 0);
        }
#pragma unroll
        for (int r = 0; r < 4; ++r)
          smD[((2 + mt) * 3 + nt) * 256 + (rb + r) * 16 + col] = d0[r] + d1[r];
      }
      LK0;
    }
    SBAR; BAR;  // E: smD ready
    if (wid >= 6) { VM0; SBAR; }  // waves 6/7: their own prefetched gate loads
    if (s <= 255) {  // h0 epilogue
      float Dr = smD[((0 + (eb >> 4)) * 3 + 0) * 256 + (eb & 15) * 16 + ejj] + b0r;
      float Dz = smD[((0 + (eb >> 4)) * 3 + 1) * 256 + (eb & 15) * 16 + ejj] + b0z;
      float Dn = smD[((0 + (eb >> 4)) * 3 + 2) * 256 + (eb & 15) * 16 + ejj] + b0n;
      float r = sigm(gxr + Dr);
      float z = sigm(gxz + Dz);
      float n = tanhfast(gxn + r * Dn);
      h0_own = (1.f - z) * n + z * h0_own;
      unsigned hv = f2b(h0_own);
      unsigned oth = __shfl_xor(hv, 1);
      if (!(ejj & 1))
        st32_g((unsigned*)(h0x + (wp0 << 14)) + (((eb << 9) + jg) >> 1), hv | (oth << 16));
    }
    if (s >= 3) {  // h1 epilogue, t = s-3
      const int t = s - 3;
      float Dr = smD[((2 + (eb >> 4)) * 3 + 0) * 256 + (eb & 15) * 16 + ejj] + b1r;
      float Dz = smD[((2 + (eb >> 4)) * 3 + 1) * 256 + (eb & 15) * 16 + ejj] + b1z;
      float Dn = smD[((2 + (eb >> 4)) * 3 + 2) * 256 + (eb & 15) * 16 + ejj] + b1n;
      float r = sigm(g1r + Dr);
      float z = sigm(g1z + Dz);
      float n = tanhfast(g1n + r * Dn);
      h1_own = (1.f - z) * n + z * h1_own;
      unsigned hv = f2b(h1_own);
      unsigned oth = __shfl_xor(hv, 1);
      if (!(ejj & 1))
        st32_g((unsigned*)(h1x + (wp1 << 14)) + (((eb << 9) + jg) >> 1), hv | (oth << 16));
      h1seq[((size_t)(t * 32 + eb) << 9) + jg] = f2b(fmaxf(h1_own, 0.f));
    }
    VM0;       // drain h/x1/h1seq stores (x1 issued early, mostly complete)
    SBAR; BAR; // I
    if (tid == 384 && s < 258)
      __hip_atomic_fetch_or(msk + (size_t)(s + 1) * 32, 1u << blk,
                            __ATOMIC_RELAXED, __HIP_MEMORY_SCOPE_AGENT);
    // tail prefetches (latency spans the next poll/frag phase)
    if (s <= 254) {
      const float* q = xg0 + (size_t)(s + 1) * 49152 + eb * 1536 + jg;
      gxr = ldf_p(q); gxz = ldf_p(q + 512); gxn = ldf_p(q + 1024);
    }
    if (s >= 2 && s <= 257) {  // X1(s-2) gates for interval s+1 (certified by msk[s])
      const float* xc = x1x + (size_t)((s - 2) & 3) * 49152 + ((eb * 3) << 9) + jg;
      g1r = ldf_g(xc); g1z = ldf_g(xc + 512); g1n = ldf_g(xc + 1024);
    }
  }
}

// ---------------- in-place log_softmax over rows of 10000 ----------------
__global__ __launch_bounds__(256) void k_logsoftmax(float* __restrict__ out) {
  const int row = blockIdx.x, tid = threadIdx.x;
  float* p = out + (size_t)row * 10000;
  const int n_own = (tid < 16) ? 40 : 39;
  float v[40];
  float mx = -3.4e38f;
#pragma unroll
  for (int i = 0; i < 40; ++i)
    if (i < n_own) { v[i] = p[i * 256 + tid]; mx = fmaxf(mx, v[i]); }
  for (int o = 32; o; o >>= 1) mx = fmaxf(mx, __shfl_xor(mx, o));
  __shared__ float sm[4], ss[4];
  if ((tid & 63) == 0) sm[tid >> 6] = mx;
  __syncthreads();
  mx = fmaxf(fmaxf(sm[0], sm[1]), fmaxf(sm[2], sm[3]));
  float s = 0.f;
#pragma unroll
  for (int i = 0; i < 40; ++i)
    if (i < n_own) s += __expf(v[i] - mx);
  for (int o = 32; o; o >>= 1) s += __shfl_xor(s, o);
  if ((tid & 63) == 0) ss[tid >> 6] = s;
  __syncthreads();
  s = ss[0] + ss[1] + ss[2] + ss[3];
  float lse = mx + __logf(s);
#pragma unroll
  for (int i = 0; i < 40; ++i)
    if (i < n_own) p[i * 256 + tid] = v[i] - lse;
}

extern "C" void kernel_launch(void* const* d_in, const int* in_sizes, int n_in,
                              void* d_out, int out_size, void* d_ws, size_t ws_size,
                              hipStream_t stream) {
  (void)in_sizes; (void)n_in; (void)out_size;
  const int*   loc    = (const int*)  d_in[0];
  const float* times  = (const float*)d_in[1];
  const int*   labels = (const int*)  d_in[2];
  const float* emb    = (const float*)d_in[3];
  const float* traj   = (const float*)d_in[4];
  const float* w_ih0  = (const float*)d_in[5];
  const float* w_hh0  = (const float*)d_in[6];
  const float* b_ih0  = (const float*)d_in[7];
  const float* b_hh0  = (const float*)d_in[8];
  const float* w_ih1  = (const float*)d_in[9];
  const float* w_hh1  = (const float*)d_in[10];
  const float* b_ih1  = (const float*)d_in[11];
  const float* b_hh1  = (const float*)d_in[12];
  const float* fc_w   = (const float*)d_in[13];
  const float* fc_b   = (const float*)d_in[14];

  if (ws_size < 31500000) return;

  char* ws = (char*)d_ws;
  size_t off = 0;
  auto alloc = [&](size_t b) { size_t r = off; off += (b + 255) & ~(size_t)255; return r; };
  unsigned* msk  = (unsigned*)(ws + alloc(259 * 32 * 4));
  u16*   h0x   = (u16*)  (ws + alloc(2 * 32 * 512 * 2));
  u16*   h1x   = (u16*)  (ws + alloc(2 * 32 * 512 * 2));
  float* x1x   = (float*)(ws + alloc((size_t)4 * 32 * 3 * 512 * 4));
  u16*   x0    = (u16*)  (ws + alloc((size_t)8192 * 288 * 2));
  u16*   wih0b = (u16*)  (ws + alloc((size_t)1536 * 288 * 2));
  u16*   whh0b = (u16*)  (ws + alloc((size_t)1536 * 512 * 2));
  u16*   wih1b = (u16*)  (ws + alloc((size_t)1536 * 512 * 2));
  u16*   whh1b = (u16*)  (ws + alloc((size_t)1536 * 512 * 2));
  u16*   fcwb  = (u16*)  (ws + alloc((size_t)10112 * 512 * 2));
  u16*   h1seq = (u16*)  (ws + alloc((size_t)8192 * 512 * 2));

  float* outp = (float*)d_out;
  float* xg0  = outp;                 // [8192][1536] scratch in d_out (dead until FC)
  float* tptr = outp + 81920000;      // time [8192]

  hipFuncSetAttribute((const void*)k_scan5, hipFuncAttributeMaxDynamicSharedMemorySize, 159744);

  hipMemsetAsync(msk, 0, 259 * 32 * 4, stream);
  k_maskinit<<<1, 64, 0, stream>>>(msk);
  k_castpad<<<1024, 256, 0, stream>>>(w_ih0, wih0b, 1536, 257, 1536, 288);
  k_castpad<<<1024, 256, 0, stream>>>(w_hh0, whh0b, 1536, 512, 1536, 512);
  k_castpad<<<1024, 256, 0, stream>>>(w_ih1, wih1b, 1536, 512, 1536, 512);
  k_castpad<<<1024, 256, 0, stream>>>(w_hh1, whh1b, 1536, 512, 1536, 512);
  k_castpad<<<1024, 256, 0, stream>>>(fc_w, fcwb, 10001, 512, 10112, 512);
  k_embed<<<2048, 256, 0, stream>>>(loc, times, emb, x0);
  k_gemm<0><<<dim3(12, 64), 256, 0, stream>>>(x0, wih0b, b_ih0, xg0, 1536, 288, nullptr);
  k_hinit<<<64, 256, 0, stream>>>(traj, labels, h0x + 16384, 0);  // h0(-1) -> parity 1
  k_hinit<<<64, 256, 0, stream>>>(traj, labels, h1x + 16384, 1);  // h1(-1) -> parity 1
  k_scan5<<<32, 512, 159744, stream>>>(xg0, whh0b, b_hh0, wih1b, b_ih1, whh1b, b_hh1,
                                       traj, labels, h0x, h1x, x1x, h1seq, msk);
  k_gemm<1><<<dim3(79, 64), 256, 0, stream>>>(h1seq, fcwb, fc_b, outp, 10112, 512, tptr);
  k_logsoftmax<<<8192, 256, 0, stream>>>(outp);
}

// Round 7
// 2444.413 us; speedup vs baseline: 1.0798x; 1.0798x over previous
//
#include <hip/hip_runtime.h>

typedef unsigned short u16;
typedef __bf16 bf16x8 __attribute__((ext_vector_type(8)));
typedef float f32x4 __attribute__((ext_vector_type(4)));

#define DEVI __device__ __forceinline__

DEVI u16 f2b(float f) {
  union { float f; unsigned u; } c; c.f = f;
  unsigned r = c.u + 0x7FFFu + ((c.u >> 16) & 1u);
  return (u16)(r >> 16);
}
DEVI float b2f(u16 u) {
  union { unsigned u; float f; } c; c.u = ((unsigned)u) << 16; return c.f;
}

DEVI float sigm(float x) { return 1.f / (1.f + __expf(-x)); }
DEVI float tanhfast(float x) {
  x = fminf(fmaxf(x, -15.f), 15.f);
  float e = __expf(2.f * x);
  return (e - 1.f) / (e + 1.f);
}

DEVI void async16(const void* g, void* l) {
  __builtin_amdgcn_global_load_lds((const __attribute__((address_space(1))) void*)g,
                                   (__attribute__((address_space(3))) void*)l, 16, 0, 0);
}

// LLC-coherent (cross-XCD) bypass ops. Caller must s_waitcnt vmcnt before
// consuming load results (rule 18).
DEVI float ldf_p(const float* p) { float r; asm volatile("global_load_dword %0, %1, off"         : "=v"(r) : "v"(p) : "memory"); return r; }
DEVI f32x4 ld16_g(const u16* p)  { f32x4 r; asm volatile("global_load_dwordx4 %0, %1, off sc0 sc1" : "=v"(r) : "v"(p) : "memory"); return r; }
DEVI void  st32_g(unsigned* p, unsigned v) { asm volatile("global_store_dword %0, %1, off sc0 sc1" :: "v"(p), "v"(v) : "memory"); }

#define VM0 asm volatile("s_waitcnt vmcnt(0)" ::: "memory")
#define LK0 asm volatile("s_waitcnt lgkmcnt(0)" ::: "memory")
#define SBAR __builtin_amdgcn_sched_barrier(0)
#define BAR __builtin_amdgcn_s_barrier()

// ---------------- cast / pad fp32 -> bf16 ----------------
__global__ __launch_bounds__(256) void k_castpad(const float* __restrict__ src, u16* __restrict__ dst,
                                                 int srows, int scols, int drows, int dcols) {
  size_t n = (size_t)drows * dcols;
  for (size_t i = blockIdx.x * 256 + threadIdx.x; i < n; i += (size_t)gridDim.x * 256) {
    int r = (int)(i / dcols), c = (int)(i % dcols);
    float v = (r < srows && c < scols) ? src[(size_t)r * scols + c] : 0.f;
    dst[i] = f2b(v);
  }
}

// ---------------- embedding + time concat -> x0 bf16 [8192][288] ----------------
__global__ __launch_bounds__(256) void k_embed(const int* __restrict__ loc, const float* __restrict__ times,
                                               const float* __restrict__ emb, u16* __restrict__ x0) {
  int m = blockIdx.x * 4 + (threadIdx.x >> 6);  // m = t*32 + b
  int s = threadIdx.x & 63;
  int b = m & 31, t = m >> 5;
  int li = loc[b * 256 + t];
  const float4* er = (const float4*)(emb + (size_t)li * 256);
  u16* xr = x0 + (size_t)m * 288;
  float4 v = er[s];
  ushort4 u;
  u.x = f2b(v.x); u.y = f2b(v.y); u.z = f2b(v.z); u.w = f2b(v.w);
  *(ushort4*)(xr + s * 4) = u;
  if (s == 0) xr[256] = f2b(times[b * 256 + t]);
  else if (s <= 31) xr[256 + s] = 0;
}

// ---------------- init h seed (bf16) from traj_emb[labels] ----------------
__global__ __launch_bounds__(256) void k_hinit(const float* __restrict__ traj, const int* __restrict__ labels,
                                               u16* __restrict__ dst, int layer) {
  int idx = blockIdx.x * 256 + threadIdx.x;
  if (idx < 16384) {
    int fidx = layer * 16384 + idx;
    dst[idx] = f2b(traj[(size_t)labels[fidx >> 10] * 1024 + (fidx & 1023)]);
  }
}

// ---------------- seed mask[0] = all 32 blocks "done" ----------------
__global__ __launch_bounds__(64) void k_maskinit(unsigned* __restrict__ msk) {
  if (threadIdx.x == 0) msk[0] = 0xFFFFFFFFu;
}

// ---------------- bf16 MFMA GEMM: C[M,N] = A[M,K] * Bw[N,K]^T (+bias) ----------------
template <int MODE>
__global__ __launch_bounds__(256) void k_gemm(const u16* __restrict__ A, const u16* __restrict__ Bw,
                                              const float* __restrict__ bias, float* __restrict__ C,
                                              int N, int K, float* __restrict__ tptr) {
  __shared__ __align__(16) u16 As[128 * 32];
  __shared__ __align__(16) u16 Bs[128 * 32];
  const int tid = threadIdx.x;
  const int lane = tid & 63, wid = tid >> 6;
  const int tn = blockIdx.x, tm = blockIdx.y;
  const int wm = wid >> 1, wn = wid & 1;

  f32x4 acc[4][4] = {};

  const int r0 = tid >> 2;
  const int cb0 = (tid * 16) & 63;

  for (int k0 = 0; k0 < K; k0 += 32) {
    __syncthreads();
#pragma unroll
    for (int p = 0; p < 2; ++p) {
      int row = r0 + p * 64;
      const u16* ga = A + (size_t)(tm * 128 + row) * K + k0 + (cb0 >> 1);
      async16(ga, (void*)(As + wid * 512 + p * 2048));
      const u16* gb = Bw + (size_t)(tn * 128 + row) * K + k0 + (cb0 >> 1);
      async16(gb, (void*)(Bs + wid * 512 + p * 2048));
    }
    asm volatile("s_waitcnt vmcnt(0)" ::: "memory");
    __syncthreads();
    bf16x8 af[4], bf[4];
#pragma unroll
    for (int i = 0; i < 4; ++i) {
      af[i] = *reinterpret_cast<const bf16x8*>(As + (wm * 64 + i * 16 + (lane & 15)) * 32 + ((lane >> 4) * 8));
      bf[i] = *reinterpret_cast<const bf16x8*>(Bs + (wn * 64 + i * 16 + (lane & 15)) * 32 + ((lane >> 4) * 8));
    }
#pragma unroll
    for (int i = 0; i < 4; ++i)
#pragma unroll
      for (int j = 0; j < 4; ++j)
        acc[i][j] = __builtin_amdgcn_mfma_f32_16x16x32_bf16(af[i], bf[j], acc[i][j], 0, 0, 0);
  }

  const int row0 = tm * 128 + wm * 64;
  const int col0 = tn * 128 + wn * 64;
#pragma unroll
  for (int i = 0; i < 4; ++i)
#pragma unroll
    for (int j = 0; j < 4; ++j)
#pragma unroll
      for (int r = 0; r < 4; ++r) {
        int row = row0 + i * 16 + ((lane >> 4) * 4) + r;
        int col = col0 + j * 16 + (lane & 15);
        float v = acc[i][j][r];
        if (MODE == 0) {
          C[(size_t)row * N + col] = v + bias[col];
        } else {
          int orow = ((row & 31) << 8) + (row >> 5);  // b*256 + t
          if (col < 10000) C[(size_t)orow * 10000 + col] = v + bias[col];
          else if (col == 10000) tptr[orow] = sigm(v + bias[col]);
        }
      }
}

// ---------------- merged persistent 2-layer GRU scan, 32 blocks ----------------
// Block blk owns h0-cols AND h1-cols [blk*16..+15]. X1 (layer-1 x-gates) for
// those columns is produced AND consumed by the same block -> pure LDS, no
// global ring. Interval s (0..256):
//   phase A: load h0(s-1) frags (LLC) -> H0 = w_hh0@h0 (s<=255, ->smD f32),
//            X1(s-1) = w_ih1@h0 (s>=1, ->smX bf16)
//   phase B: load h1(s-2) frags into SAME regs -> H1 = w_hh1@h1 (s>=1, ->smD)
//   epilogue: h0(s) update+publish; h1(s-1) = GRU1(smX+bias, H1) -> h1x, h1seq
// Sync: one bitmask dword per interval; wave7 polls with s_sleep backoff; one
// fetch_or per block after a full store drain. Serial two-phase frag loads
// keep max 64 frag VGPRs live (r6's 128-live spilled to scratch: VGPR=108).
// LDS: 147456 weights + 12288 smD(f32 H0|H1) + 3072 smX(bf16) = 162816.
__global__ __launch_bounds__(512, 2)
void k_scan6(const float* __restrict__ xg0,
             const u16* __restrict__ whh0, const float* __restrict__ bhh0,
             const u16* __restrict__ wih1, const float* __restrict__ bih1,
             const u16* __restrict__ whh1, const float* __restrict__ bhh1,
             const float* __restrict__ traj, const int* __restrict__ labels,
             u16* __restrict__ h0x, u16* __restrict__ h1x,
             u16* __restrict__ h1seq, unsigned* __restrict__ msk)
{
  extern __shared__ __align__(16) char dynlds[];
  float* smD = (float*)(dynlds + 147456);        // 12 tiles f32: H0=0..5, H1=6..11
  u16*   smX = (u16*)(dynlds + 147456 + 12288);  // 6 tiles bf16 (X1)

  const int tid = threadIdx.x, blk = blockIdx.x;
  const int lane = tid & 63, wid = tid >> 6;
  const int eb = tid >> 4, ejj = tid & 15;
  const int jg = (blk << 4) + ejj;

  // ---- LDS preload: whh0 / wih1 / whh1 block-slices [48][512], XOR-swizzled ----
#pragma unroll
  for (int m = 0; m < 3; ++m) {
    const u16* srcm = (m == 0) ? whh0 : (m == 1) ? wih1 : whh1;
    char* dst = dynlds + m * 49152;
    for (int c = tid; c < 3072; c += 512) {
      int row = c >> 6, o16 = c & 63;
      int grow = (row >> 4) * 512 + (blk << 4) + (row & 15);
      const float4* src = (const float4*)(srcm + (size_t)grow * 512 + o16 * 8);
      int byte = (row << 10) + ((o16 * 16) ^ ((row & 7) << 4));
      *(float4*)(dst + byte) = *src;
    }
  }

  float h0_own, h1_own;
  {
    int f0 = eb * 512 + jg;
    h0_own = traj[(size_t)labels[f0 >> 10] * 1024 + (f0 & 1023)];
    int f1 = 16384 + eb * 512 + jg;
    h1_own = traj[(size_t)labels[f1 >> 10] * 1024 + (f1 & 1023)];
  }
  const float b0r = bhh0[jg], b0z = bhh0[512 + jg], b0n = bhh0[1024 + jg];
  const float b1r = bhh1[jg], b1z = bhh1[512 + jg], b1n = bhh1[1024 + jg];
  const float bi1r = bih1[jg], bi1z = bih1[512 + jg], bi1n = bih1[1024 + jg];

  const int mt = (wid < 6) ? wid / 3 : 0, nt = (wid < 6) ? wid % 3 : 0;

  __syncthreads();

  // layer-0 gate prefetch registers (interval s values)
  float gxr = 0.f, gxz = 0.f, gxn = 0.f;
  {
    const float* q = xg0 + (size_t)eb * 1536 + jg;
    gxr = ldf_p(q); gxz = ldf_p(q + 512); gxn = ldf_p(q + 1024);
  }

  for (int s = 0; s <= 256; ++s) {
    const int rp0 = (s + 1) & 1;  // h0(s-1) parity
    const int wp0 = s & 1;        // h0(s) parity
    const int rp1 = s & 1;        // h1(s-2) parity
    const int wp1 = (s + 1) & 1;  // h1(s-1) parity

    if (wid == 7) {
      const unsigned* mp = msk + (size_t)s * 32;
      while (__hip_atomic_load(mp, __ATOMIC_RELAXED, __HIP_MEMORY_SCOPE_AGENT) != 0xFFFFFFFFu)
        __builtin_amdgcn_s_sleep(1);
    }
    BAR;  // C: h0(s-1), h1(s-2) certified at LLC

    if (wid < 6) {
      const int col = lane & 15, hi = lane >> 4, rb = hi << 2;
      const int cb = hi << 4;
      const int swz = ((col & 7) << 4);
      const int rowoff = (nt * 16 + col) << 10;
      f32x4 afr[16];
      // ---- phase A: h0(s-1) fragments ----
      {
        const u16* hs = h0x + (rp0 << 14) + ((mt * 16 + col) << 9) + (hi * 8);
#pragma unroll
        for (int ks = 0; ks < 16; ++ks) afr[ks] = ld16_g(hs + ks * 32);
      }
      VM0; SBAR;   // also drains this wave's gate prefetches
      if (s <= 255) {  // H0 = w_hh0 @ h0
        f32x4 a0 = {0.f, 0.f, 0.f, 0.f}, a1 = {0.f, 0.f, 0.f, 0.f};
#pragma unroll
        for (int ks = 0; ks < 8; ++ks) {
          bf16x8 w0 = *(const bf16x8*)(dynlds + rowoff + (((2 * ks) * 64 + cb) ^ swz));
          bf16x8 w1 = *(const bf16x8*)(dynlds + rowoff + (((2 * ks + 1) * 64 + cb) ^ swz));
          a0 = __builtin_amdgcn_mfma_f32_16x16x32_bf16(__builtin_bit_cast(bf16x8, afr[2 * ks]),     w0, a0, 0, 0, 0);
          a1 = __builtin_amdgcn_mfma_f32_16x16x32_bf16(__builtin_bit_cast(bf16x8, afr[2 * ks + 1]), w1, a1, 0, 0, 0);
        }
#pragma unroll
        for (int r = 0; r < 4; ++r)
          smD[(mt * 3 + nt) * 256 + (rb + r) * 16 + col] = a0[r] + a1[r];
      }
      if (s >= 1) {  // X1(s-1) = w_ih1 @ h0 -> bf16 LDS
        f32x4 c0 = {0.f, 0.f, 0.f, 0.f}, c1 = {0.f, 0.f, 0.f, 0.f};
#pragma unroll
        for (int ks = 0; ks < 8; ++ks) {
          bf16x8 w0 = *(const bf16x8*)(dynlds + 49152 + rowoff + (((2 * ks) * 64 + cb) ^ swz));
          bf16x8 w1 = *(const bf16x8*)(dynlds + 49152 + rowoff + (((2 * ks + 1) * 64 + cb) ^ swz));
          c0 = __builtin_amdgcn_mfma_f32_16x16x32_bf16(__builtin_bit_cast(bf16x8, afr[2 * ks]),     w0, c0, 0, 0, 0);
          c1 = __builtin_amdgcn_mfma_f32_16x16x32_bf16(__builtin_bit_cast(bf16x8, afr[2 * ks + 1]), w1, c1, 0, 0, 0);
        }
#pragma unroll
        for (int r = 0; r < 4; ++r)
          smX[(mt * 3 + nt) * 256 + (rb + r) * 16 + col] = f2b(c0[r] + c1[r]);
      }
      // ---- phase B: h1(s-2) fragments (reuse afr regs -> no spill) ----
      if (s >= 1) {
        const u16* hs = h1x + (rp1 << 14) + ((mt * 16 + col) << 9) + (hi * 8);
#pragma unroll
        for (int ks = 0; ks < 16; ++ks) afr[ks] = ld16_g(hs + ks * 32);
        VM0; SBAR;
        f32x4 d0 = {0.f, 0.f, 0.f, 0.f}, d1 = {0.f, 0.f, 0.f, 0.f};
#pragma unroll
        for (int ks = 0; ks < 8; ++ks) {
          bf16x8 w0 = *(const bf16x8*)(dynlds + 98304 + rowoff + (((2 * ks) * 64 + cb) ^ swz));
          bf16x8 w1 = *(const bf16x8*)(dynlds + 98304 + rowoff + (((2 * ks + 1) * 64 + cb) ^ swz));
          d0 = __builtin_amdgcn_mfma_f32_16x16x32_bf16(__builtin_bit_cast(bf16x8, afr[2 * ks]),     w0, d0, 0, 0, 0);
          d1 = __builtin_amdgcn_mfma_f32_16x16x32_bf16(__builtin_bit_cast(bf16x8, afr[2 * ks + 1]), w1, d1, 0, 0, 0);
        }
#pragma unroll
        for (int r = 0; r < 4; ++r)
          smD[(6 + mt * 3 + nt) * 256 + (rb + r) * 16 + col] = d0[r] + d1[r];
      }
      LK0;
    }
    SBAR; BAR;  // E: smD/smX ready
    if (wid >= 6) { VM0; SBAR; }  // waves 6/7: drain their own gate prefetches

    if (s <= 255) {  // h0 epilogue
      float Dr = smD[((eb >> 4) * 3 + 0) * 256 + (eb & 15) * 16 + ejj] + b0r;
      float Dz = smD[((eb >> 4) * 3 + 1) * 256 + (eb & 15) * 16 + ejj] + b0z;
      float Dn = smD[((eb >> 4) * 3 + 2) * 256 + (eb & 15) * 16 + ejj] + b0n;
      float r = sigm(gxr + Dr);
      float z = sigm(gxz + Dz);
      float n = tanhfast(gxn + r * Dn);
      h0_own = (1.f - z) * n + z * h0_own;
      unsigned hv = f2b(h0_own);
      unsigned oth = __shfl_xor(hv, 1);
      if (!(ejj & 1))
        st32_g((unsigned*)(h0x + (wp0 << 14)) + (((eb << 9) + jg) >> 1), hv | (oth << 16));
    }
    if (s >= 1) {  // h1 epilogue, t = s-1; X1 from LDS (same block produced it)
      const int t = s - 1;
      float xr = b2f(smX[((eb >> 4) * 3 + 0) * 256 + (eb & 15) * 16 + ejj]) + bi1r;
      float xz = b2f(smX[((eb >> 4) * 3 + 1) * 256 + (eb & 15) * 16 + ejj]) + bi1z;
      float xn = b2f(smX[((eb >> 4) * 3 + 2) * 256 + (eb & 15) * 16 + ejj]) + bi1n;
      float Dr = smD[(6 + (eb >> 4) * 3 + 0) * 256 + (eb & 15) * 16 + ejj] + b1r;
      float Dz = smD[(6 + (eb >> 4) * 3 + 1) * 256 + (eb & 15) * 16 + ejj] + b1z;
      float Dn = smD[(6 + (eb >> 4) * 3 + 2) * 256 + (eb & 15) * 16 + ejj] + b1n;
      float r = sigm(xr + Dr);
      float z = sigm(xz + Dz);
      float n = tanhfast(xn + r * Dn);
      h1_own = (1.f - z) * n + z * h1_own;
      unsigned hv = f2b(h1_own);
      unsigned oth = __shfl_xor(hv, 1);
      if (!(ejj & 1))
        st32_g((unsigned*)(h1x + (wp1 << 14)) + (((eb << 9) + jg) >> 1), hv | (oth << 16));
      h1seq[((size_t)(t * 32 + eb) << 9) + jg] = f2b(fmaxf(h1_own, 0.f));
    }
    VM0;       // all h stores acked at LLC
    SBAR; BAR; // I
    if (tid == 384 && s <= 255)
      __hip_atomic_fetch_or(msk + (size_t)(s + 1) * 32, 1u << blk,
                            __ATOMIC_RELAXED, __HIP_MEMORY_SCOPE_AGENT);
    if (s <= 254) {  // prefetch next xg0 (all waves)
      const float* q = xg0 + (size_t)(s + 1) * 49152 + eb * 1536 + jg;
      gxr = ldf_p(q); gxz = ldf_p(q + 512); gxn = ldf_p(q + 1024);
    }
  }
}

// ---------------- in-place log_softmax over rows of 10000 ----------------
__global__ __launch_bounds__(256) void k_logsoftmax(float* __restrict__ out) {
  const int row = blockIdx.x, tid = threadIdx.x;
  float* p = out + (size_t)row * 10000;
  const int n_own = (tid < 16) ? 40 : 39;
  float v[40];
  float mx = -3.4e38f;
#pragma unroll
  for (int i = 0; i < 40; ++i)
    if (i < n_own) { v[i] = p[i * 256 + tid]; mx = fmaxf(mx, v[i]); }
  for (int o = 32; o; o >>= 1) mx = fmaxf(mx, __shfl_xor(mx, o));
  __shared__ float sm[4], ss[4];
  if ((tid & 63) == 0) sm[tid >> 6] = mx;
  __syncthreads();
  mx = fmaxf(fmaxf(sm[0], sm[1]), fmaxf(sm[2], sm[3]));
  float s = 0.f;
#pragma unroll
  for (int i = 0; i < 40; ++i)
    if (i < n_own) s += __expf(v[i] - mx);
  for (int o = 32; o; o >>= 1) s += __shfl_xor(s, o);
  if ((tid & 63) == 0) ss[tid >> 6] = s;
  __syncthreads();
  s = ss[0] + ss[1] + ss[2] + ss[3];
  float lse = mx + __logf(s);
#pragma unroll
  for (int i = 0; i < 40; ++i)
    if (i < n_own) p[i * 256 + tid] = v[i] - lse;
}

extern "C" void kernel_launch(void* const* d_in, const int* in_sizes, int n_in,
                              void* d_out, int out_size, void* d_ws, size_t ws_size,
                              hipStream_t stream) {
  (void)in_sizes; (void)n_in; (void)out_size;
  const int*   loc    = (const int*)  d_in[0];
  const float* times  = (const float*)d_in[1];
  const int*   labels = (const int*)  d_in[2];
  const float* emb    = (const float*)d_in[3];
  const float* traj   = (const float*)d_in[4];
  const float* w_ih0  = (const float*)d_in[5];
  const float* w_hh0  = (const float*)d_in[6];
  const float* b_ih0  = (const float*)d_in[7];
  const float* b_hh0  = (const float*)d_in[8];
  const float* w_ih1  = (const float*)d_in[9];
  const float* w_hh1  = (const float*)d_in[10];
  const float* b_ih1  = (const float*)d_in[11];
  const float* b_hh1  = (const float*)d_in[12];
  const float* fc_w   = (const float*)d_in[13];
  const float* fc_b   = (const float*)d_in[14];

  if (ws_size < 31500000) return;

  char* ws = (char*)d_ws;
  size_t off = 0;
  auto alloc = [&](size_t b) { size_t r = off; off += (b + 255) & ~(size_t)255; return r; };
  unsigned* msk  = (unsigned*)(ws + alloc(260 * 32 * 4));
  u16*   h0x   = (u16*)  (ws + alloc(2 * 32 * 512 * 2));
  u16*   h1x   = (u16*)  (ws + alloc(2 * 32 * 512 * 2));
  u16*   x0    = (u16*)  (ws + alloc((size_t)8192 * 288 * 2));
  u16*   wih0b = (u16*)  (ws + alloc((size_t)1536 * 288 * 2));
  u16*   whh0b = (u16*)  (ws + alloc((size_t)1536 * 512 * 2));
  u16*   wih1b = (u16*)  (ws + alloc((size_t)1536 * 512 * 2));
  u16*   whh1b = (u16*)  (ws + alloc((size_t)1536 * 512 * 2));
  u16*   fcwb  = (u16*)  (ws + alloc((size_t)10112 * 512 * 2));
  u16*   h1seq = (u16*)  (ws + alloc((size_t)8192 * 512 * 2));

  float* outp = (float*)d_out;
  float* xg0  = outp;                 // [8192][1536] scratch in d_out (dead until FC)
  float* tptr = outp + 81920000;      // time [8192]

  hipFuncSetAttribute((const void*)k_scan6, hipFuncAttributeMaxDynamicSharedMemorySize, 162816);

  hipMemsetAsync(msk, 0, 260 * 32 * 4, stream);
  k_maskinit<<<1, 64, 0, stream>>>(msk);
  k_castpad<<<1024, 256, 0, stream>>>(w_ih0, wih0b, 1536, 257, 1536, 288);
  k_castpad<<<1024, 256, 0, stream>>>(w_hh0, whh0b, 1536, 512, 1536, 512);
  k_castpad<<<1024, 256, 0, stream>>>(w_ih1, wih1b, 1536, 512, 1536, 512);
  k_castpad<<<1024, 256, 0, stream>>>(w_hh1, whh1b, 1536, 512, 1536, 512);
  k_castpad<<<1024, 256, 0, stream>>>(fc_w, fcwb, 10001, 512, 10112, 512);
  k_embed<<<2048, 256, 0, stream>>>(loc, times, emb, x0);
  k_gemm<0><<<dim3(12, 64), 256, 0, stream>>>(x0, wih0b, b_ih0, xg0, 1536, 288, nullptr);
  k_hinit<<<64, 256, 0, stream>>>(traj, labels, h0x + 16384, 0);  // h0(-1) -> parity 1
  k_hinit<<<64, 256, 0, stream>>>(traj, labels, h1x + 16384, 1);  // h1(-1) -> parity 1
  k_scan6<<<32, 512, 162816, stream>>>(xg0, whh0b, b_hh0, wih1b, b_ih1, whh1b, b_hh1,
                                       traj, labels, h0x, h1x, h1seq, msk);
  k_gemm<1><<<dim3(79, 64), 256, 0, stream>>>(h1seq, fcwb, fc_b, outp, 10112, 512, tptr);
  k_logsoftmax<<<8192, 256, 0, stream>>>(outp);
}

// Round 8
// 1960.449 us; speedup vs baseline: 1.3464x; 1.2469x over previous
//
#include <hip/hip_runtime.h>

typedef unsigned short u16;
typedef __bf16 bf16x8 __attribute__((ext_vector_type(8)));
typedef float f32x4 __attribute__((ext_vector_type(4)));

#define DEVI __device__ __forceinline__

DEVI u16 f2b(float f) {
  union { float f; unsigned u; } c; c.f = f;
  unsigned r = c.u + 0x7FFFu + ((c.u >> 16) & 1u);
  return (u16)(r >> 16);
}
DEVI float b2f(u16 u) {
  union { unsigned u; float f; } c; c.u = ((unsigned)u) << 16; return c.f;
}

DEVI float sigm(float x) { return 1.f / (1.f + __expf(-x)); }
DEVI float tanhfast(float x) {
  x = fminf(fmaxf(x, -15.f), 15.f);
  float e = __expf(2.f * x);
  return (e - 1.f) / (e + 1.f);
}

DEVI void async16(const void* g, void* l) {
  __builtin_amdgcn_global_load_lds((const __attribute__((address_space(1))) void*)g,
                                   (__attribute__((address_space(3))) void*)l, 16, 0, 0);
}

// LLC-coherent (cross-XCD) bypass ops. Caller must s_waitcnt vmcnt before
// consuming load results (rule 18).
DEVI float    ldf_p(const float* p)    { float r;    asm volatile("global_load_dword %0, %1, off"         : "=v"(r) : "v"(p) : "memory"); return r; }
DEVI unsigned ld32_g(const unsigned* p){ unsigned r; asm volatile("global_load_dword %0, %1, off sc0 sc1" : "=v"(r) : "v"(p) : "memory"); return r; }
DEVI f32x4    ld16_g(const u16* p)     { f32x4 r;    asm volatile("global_load_dwordx4 %0, %1, off sc0 sc1" : "=v"(r) : "v"(p) : "memory"); return r; }
DEVI void     st32_g(unsigned* p, unsigned v) { asm volatile("global_store_dword %0, %1, off sc0 sc1" :: "v"(p), "v"(v) : "memory"); }

#define VM0 asm volatile("s_waitcnt vmcnt(0)" ::: "memory")
#define LK0 asm volatile("s_waitcnt lgkmcnt(0)" ::: "memory")
#define SBAR __builtin_amdgcn_sched_barrier(0)
#define BAR __builtin_amdgcn_s_barrier()

// ---------------- cast / pad fp32 -> bf16 ----------------
__global__ __launch_bounds__(256) void k_castpad(const float* __restrict__ src, u16* __restrict__ dst,
                                                 int srows, int scols, int drows, int dcols) {
  size_t n = (size_t)drows * dcols;
  for (size_t i = blockIdx.x * 256 + threadIdx.x; i < n; i += (size_t)gridDim.x * 256) {
    int r = (int)(i / dcols), c = (int)(i % dcols);
    float v = (r < srows && c < scols) ? src[(size_t)r * scols + c] : 0.f;
    dst[i] = f2b(v);
  }
}

// ---------------- embedding + time concat -> x0 bf16 [8192][288] ----------------
__global__ __launch_bounds__(256) void k_embed(const int* __restrict__ loc, const float* __restrict__ times,
                                               const float* __restrict__ emb, u16* __restrict__ x0) {
  int m = blockIdx.x * 4 + (threadIdx.x >> 6);  // m = t*32 + b
  int s = threadIdx.x & 63;
  int b = m & 31, t = m >> 5;
  int li = loc[b * 256 + t];
  const float4* er = (const float4*)(emb + (size_t)li * 256);
  u16* xr = x0 + (size_t)m * 288;
  float4 v = er[s];
  ushort4 u;
  u.x = f2b(v.x); u.y = f2b(v.y); u.z = f2b(v.z); u.w = f2b(v.w);
  *(ushort4*)(xr + s * 4) = u;
  if (s == 0) xr[256] = f2b(times[b * 256 + t]);
  else if (s <= 31) xr[256 + s] = 0;
}

// ---------------- init h seed (bf16) from traj_emb[labels] ----------------
__global__ __launch_bounds__(256) void k_hinit(const float* __restrict__ traj, const int* __restrict__ labels,
                                               u16* __restrict__ dst, int layer) {
  int idx = blockIdx.x * 256 + threadIdx.x;
  if (idx < 16384) {
    int fidx = layer * 16384 + idx;
    dst[idx] = f2b(traj[(size_t)labels[fidx >> 10] * 1024 + (fidx & 1023)]);
  }
}

// ---------------- seed msk[rep][0][blk] = 1 (4 replicas x 32 blocks) ----------------
__global__ __launch_bounds__(128) void k_maskinit(unsigned* __restrict__ msk) {
  int t = threadIdx.x;  // t = rep*32 + blk
  msk[(size_t)(t >> 5) * 258 * 32 + (t & 31)] = 1u;
}

// ---------------- bf16 MFMA GEMM: C[M,N] = A[M,K] * Bw[N,K]^T (+bias) ----------------
template <int MODE>
__global__ __launch_bounds__(256) void k_gemm(const u16* __restrict__ A, const u16* __restrict__ Bw,
                                              const float* __restrict__ bias, float* __restrict__ C,
                                              int N, int K, float* __restrict__ tptr) {
  __shared__ __align__(16) u16 As[128 * 32];
  __shared__ __align__(16) u16 Bs[128 * 32];
  const int tid = threadIdx.x;
  const int lane = tid & 63, wid = tid >> 6;
  const int tn = blockIdx.x, tm = blockIdx.y;
  const int wm = wid >> 1, wn = wid & 1;

  f32x4 acc[4][4] = {};

  const int r0 = tid >> 2;
  const int cb0 = (tid * 16) & 63;

  for (int k0 = 0; k0 < K; k0 += 32) {
    __syncthreads();
#pragma unroll
    for (int p = 0; p < 2; ++p) {
      int row = r0 + p * 64;
      const u16* ga = A + (size_t)(tm * 128 + row) * K + k0 + (cb0 >> 1);
      async16(ga, (void*)(As + wid * 512 + p * 2048));
      const u16* gb = Bw + (size_t)(tn * 128 + row) * K + k0 + (cb0 >> 1);
      async16(gb, (void*)(Bs + wid * 512 + p * 2048));
    }
    asm volatile("s_waitcnt vmcnt(0)" ::: "memory");
    __syncthreads();
    bf16x8 af[4], bf[4];
#pragma unroll
    for (int i = 0; i < 4; ++i) {
      af[i] = *reinterpret_cast<const bf16x8*>(As + (wm * 64 + i * 16 + (lane & 15)) * 32 + ((lane >> 4) * 8));
      bf[i] = *reinterpret_cast<const bf16x8*>(Bs + (wn * 64 + i * 16 + (lane & 15)) * 32 + ((lane >> 4) * 8));
    }
#pragma unroll
    for (int i = 0; i < 4; ++i)
#pragma unroll
      for (int j = 0; j < 4; ++j)
        acc[i][j] = __builtin_amdgcn_mfma_f32_16x16x32_bf16(af[i], bf[j], acc[i][j], 0, 0, 0);
  }

  const int row0 = tm * 128 + wm * 64;
  const int col0 = tn * 128 + wn * 64;
#pragma unroll
  for (int i = 0; i < 4; ++i)
#pragma unroll
    for (int j = 0; j < 4; ++j)
#pragma unroll
      for (int r = 0; r < 4; ++r) {
        int row = row0 + i * 16 + ((lane >> 4) * 4) + r;
        int col = col0 + j * 16 + (lane & 15);
        float v = acc[i][j][r];
        if (MODE == 0) {
          C[(size_t)row * N + col] = v + bias[col];
        } else {
          int orow = ((row & 31) << 8) + (row >> 5);  // b*256 + t
          if (col < 10000) C[(size_t)orow * 10000 + col] = v + bias[col];
          else if (col == 10000) tptr[orow] = sigm(v + bias[col]);
        }
      }
}

// ---------------- merged persistent 2-layer GRU scan, 32 blocks (v7) ----------------
// r7 regression diagnosis baked in:
//  - fetch_or RMW on one MALL dword serialized 32 blocks -> per-writer plain
//    flag stores (4 replicas) + wave7 ballot poll (r3-proven).
//  - serial two-phase frag loads -> 4 dedup'd MFMA waves loading in PARALLEL:
//    waves 0-1 (mt=wid): h0 frags, H0+X1 MFMAs (3 gates each, no nt-redundancy)
//    waves 2-3 (mt=wid-2): h1 frags, H1 MFMAs. 64KB LLC reads/blk/interval
//    (was 192KB), one VM0 per wave, max 64 frag VGPRs -> no spill.
// Everything else identical to passing r7 kernel.
__global__ __launch_bounds__(512, 2)
void k_scan7(const float* __restrict__ xg0,
             const u16* __restrict__ whh0, const float* __restrict__ bhh0,
             const u16* __restrict__ wih1, const float* __restrict__ bih1,
             const u16* __restrict__ whh1, const float* __restrict__ bhh1,
             const float* __restrict__ traj, const int* __restrict__ labels,
             u16* __restrict__ h0x, u16* __restrict__ h1x,
             u16* __restrict__ h1seq, unsigned* __restrict__ msk)
{
  extern __shared__ __align__(16) char dynlds[];
  float* smD = (float*)(dynlds + 147456);        // 12 tiles f32: H0=0..5, H1=6..11
  u16*   smX = (u16*)(dynlds + 147456 + 12288);  // 6 tiles bf16 (X1)

  const int tid = threadIdx.x, blk = blockIdx.x;
  const int lane = tid & 63, wid = tid >> 6;
  const int eb = tid >> 4, ejj = tid & 15;
  const int jg = (blk << 4) + ejj;

  // ---- LDS preload: whh0 / wih1 / whh1 block-slices [48][512], XOR-swizzled ----
#pragma unroll
  for (int m = 0; m < 3; ++m) {
    const u16* srcm = (m == 0) ? whh0 : (m == 1) ? wih1 : whh1;
    char* dst = dynlds + m * 49152;
    for (int c = tid; c < 3072; c += 512) {
      int row = c >> 6, o16 = c & 63;
      int grow = (row >> 4) * 512 + (blk << 4) + (row & 15);
      const float4* src = (const float4*)(srcm + (size_t)grow * 512 + o16 * 8);
      int byte = (row << 10) + ((o16 * 16) ^ ((row & 7) << 4));
      *(float4*)(dst + byte) = *src;
    }
  }

  float h0_own, h1_own;
  {
    int f0 = eb * 512 + jg;
    h0_own = traj[(size_t)labels[f0 >> 10] * 1024 + (f0 & 1023)];
    int f1 = 16384 + eb * 512 + jg;
    h1_own = traj[(size_t)labels[f1 >> 10] * 1024 + (f1 & 1023)];
  }
  const float b0r = bhh0[jg], b0z = bhh0[512 + jg], b0n = bhh0[1024 + jg];
  const float b1r = bhh1[jg], b1z = bhh1[512 + jg], b1n = bhh1[1024 + jg];
  const float bi1r = bih1[jg], bi1z = bih1[512 + jg], bi1n = bih1[1024 + jg];

  __syncthreads();

  // layer-0 gate prefetch registers (interval s values)
  float gxr = 0.f, gxz = 0.f, gxn = 0.f;
  {
    const float* q = xg0 + (size_t)eb * 1536 + jg;
    gxr = ldf_p(q); gxz = ldf_p(q + 512); gxn = ldf_p(q + 1024);
  }

  for (int s = 0; s <= 256; ++s) {
    const int rp0 = (s + 1) & 1;  // h0(s-1) parity
    const int wp0 = s & 1;        // h0(s) parity
    const int rp1 = s & 1;        // h1(s-2) parity
    const int wp1 = (s + 1) & 1;  // h1(s-1) parity

    if (wid == 7) {
      const unsigned* mp = msk + ((size_t)((blk & 3) * 258 + s)) * 32 + (lane & 31);
      while (1) {
        unsigned v = ld32_g(mp);
        VM0; SBAR;
        if (__ballot(v != 0) == ~0ull) break;
      }
    }
    BAR;  // C: h0(s-1), h1(s-2) certified at LLC

    if (wid < 2) {
      // ---- h0 path: mt = wid; load h0(s-1) frags once, all 3 gates ----
      const int mt = wid;
      const int col = lane & 15, hi = lane >> 4, rb = hi << 2;
      const int cb = hi << 4;
      const int swz = ((col & 7) << 4);
      f32x4 afr[16];
      {
        const u16* hs = h0x + (rp0 << 14) + ((mt * 16 + col) << 9) + (hi * 8);
#pragma unroll
        for (int ks = 0; ks < 16; ++ks) afr[ks] = ld16_g(hs + ks * 32);
      }
      VM0; SBAR;   // also drains this wave's gate prefetches
      if (s <= 255) {  // H0 = w_hh0 @ h0
#pragma unroll
        for (int nt = 0; nt < 3; ++nt) {
          const int rowoff = (nt * 16 + col) << 10;
          f32x4 a0 = {0.f, 0.f, 0.f, 0.f}, a1 = {0.f, 0.f, 0.f, 0.f};
#pragma unroll
          for (int ks = 0; ks < 8; ++ks) {
            bf16x8 w0 = *(const bf16x8*)(dynlds + rowoff + (((2 * ks) * 64 + cb) ^ swz));
            bf16x8 w1 = *(const bf16x8*)(dynlds + rowoff + (((2 * ks + 1) * 64 + cb) ^ swz));
            a0 = __builtin_amdgcn_mfma_f32_16x16x32_bf16(__builtin_bit_cast(bf16x8, afr[2 * ks]),     w0, a0, 0, 0, 0);
            a1 = __builtin_amdgcn_mfma_f32_16x16x32_bf16(__builtin_bit_cast(bf16x8, afr[2 * ks + 1]), w1, a1, 0, 0, 0);
          }
#pragma unroll
          for (int r = 0; r < 4; ++r)
            smD[(mt * 3 + nt) * 256 + (rb + r) * 16 + col] = a0[r] + a1[r];
        }
      }
      if (s >= 1) {  // X1(s-1) = w_ih1 @ h0 -> bf16 LDS
#pragma unroll
        for (int nt = 0; nt < 3; ++nt) {
          const int rowoff = (nt * 16 + col) << 10;
          f32x4 c0 = {0.f, 0.f, 0.f, 0.f}, c1 = {0.f, 0.f, 0.f, 0.f};
#pragma unroll
          for (int ks = 0; ks < 8; ++ks) {
            bf16x8 w0 = *(const bf16x8*)(dynlds + 49152 + rowoff + (((2 * ks) * 64 + cb) ^ swz));
            bf16x8 w1 = *(const bf16x8*)(dynlds + 49152 + rowoff + (((2 * ks + 1) * 64 + cb) ^ swz));
            c0 = __builtin_amdgcn_mfma_f32_16x16x32_bf16(__builtin_bit_cast(bf16x8, afr[2 * ks]),     w0, c0, 0, 0, 0);
            c1 = __builtin_amdgcn_mfma_f32_16x16x32_bf16(__builtin_bit_cast(bf16x8, afr[2 * ks + 1]), w1, c1, 0, 0, 0);
          }
#pragma unroll
          for (int r = 0; r < 4; ++r)
            smX[(mt * 3 + nt) * 256 + (rb + r) * 16 + col] = f2b(c0[r] + c1[r]);
        }
      }
      LK0;
    } else if (wid < 4) {
      // ---- h1 path: mt = wid-2; load h1(s-2) frags in PARALLEL with h0 path ----
      const int mt = wid - 2;
      const int col = lane & 15, hi = lane >> 4, rb = hi << 2;
      const int cb = hi << 4;
      const int swz = ((col & 7) << 4);
      if (s >= 1) {
        f32x4 afr[16];
        const u16* hs = h1x + (rp1 << 14) + ((mt * 16 + col) << 9) + (hi * 8);
#pragma unroll
        for (int ks = 0; ks < 16; ++ks) afr[ks] = ld16_g(hs + ks * 32);
        VM0; SBAR;
#pragma unroll
        for (int nt = 0; nt < 3; ++nt) {
          const int rowoff = (nt * 16 + col) << 10;
          f32x4 d0 = {0.f, 0.f, 0.f, 0.f}, d1 = {0.f, 0.f, 0.f, 0.f};
#pragma unroll
          for (int ks = 0; ks < 8; ++ks) {
            bf16x8 w0 = *(const bf16x8*)(dynlds + 98304 + rowoff + (((2 * ks) * 64 + cb) ^ swz));
            bf16x8 w1 = *(const bf16x8*)(dynlds + 98304 + rowoff + (((2 * ks + 1) * 64 + cb) ^ swz));
            d0 = __builtin_amdgcn_mfma_f32_16x16x32_bf16(__builtin_bit_cast(bf16x8, afr[2 * ks]),     w0, d0, 0, 0, 0);
            d1 = __builtin_amdgcn_mfma_f32_16x16x32_bf16(__builtin_bit_cast(bf16x8, afr[2 * ks + 1]), w1, d1, 0, 0, 0);
          }
#pragma unroll
          for (int r = 0; r < 4; ++r)
            smD[(6 + mt * 3 + nt) * 256 + (rb + r) * 16 + col] = d0[r] + d1[r];
        }
      } else {
        VM0; SBAR;  // drain own gate prefetches
      }
      LK0;
    }
    SBAR; BAR;  // E: smD/smX ready
    if (wid >= 4) { VM0; SBAR; }  // waves 4-7: drain their own gate prefetches

    if (s <= 255) {  // h0 epilogue
      float Dr = smD[((eb >> 4) * 3 + 0) * 256 + (eb & 15) * 16 + ejj] + b0r;
      float Dz = smD[((eb >> 4) * 3 + 1) * 256 + (eb & 15) * 16 + ejj] + b0z;
      float Dn = smD[((eb >> 4) * 3 + 2) * 256 + (eb & 15) * 16 + ejj] + b0n;
      float r = sigm(gxr + Dr);
      float z = sigm(gxz + Dz);
      float n = tanhfast(gxn + r * Dn);
      h0_own = (1.f - z) * n + z * h0_own;
      unsigned hv = f2b(h0_own);
      unsigned oth = __shfl_xor(hv, 1);
      if (!(ejj & 1))
        st32_g((unsigned*)(h0x + (wp0 << 14)) + (((eb << 9) + jg) >> 1), hv | (oth << 16));
    }
    if (s >= 1) {  // h1 epilogue, t = s-1; X1 from LDS (same block produced it)
      const int t = s - 1;
      float xr = b2f(smX[((eb >> 4) * 3 + 0) * 256 + (eb & 15) * 16 + ejj]) + bi1r;
      float xz = b2f(smX[((eb >> 4) * 3 + 1) * 256 + (eb & 15) * 16 + ejj]) + bi1z;
      float xn = b2f(smX[((eb >> 4) * 3 + 2) * 256 + (eb & 15) * 16 + ejj]) + bi1n;
      float Dr = smD[(6 + (eb >> 4) * 3 + 0) * 256 + (eb & 15) * 16 + ejj] + b1r;
      float Dz = smD[(6 + (eb >> 4) * 3 + 1) * 256 + (eb & 15) * 16 + ejj] + b1z;
      float Dn = smD[(6 + (eb >> 4) * 3 + 2) * 256 + (eb & 15) * 16 + ejj] + b1n;
      float r = sigm(xr + Dr);
      float z = sigm(xz + Dz);
      float n = tanhfast(xn + r * Dn);
      h1_own = (1.f - z) * n + z * h1_own;
      unsigned hv = f2b(h1_own);
      unsigned oth = __shfl_xor(hv, 1);
      if (!(ejj & 1))
        st32_g((unsigned*)(h1x + (wp1 << 14)) + (((eb << 9) + jg) >> 1), hv | (oth << 16));
      h1seq[((size_t)(t * 32 + eb) << 9) + jg] = f2b(fmaxf(h1_own, 0.f));
    }
    VM0;       // all h stores acked at LLC
    SBAR; BAR; // I
    if (tid == 384 && s <= 255) {  // wave6 lane0: per-block flag stores, 4 replicas
#pragma unroll
      for (int rp = 0; rp < 4; ++rp)
        st32_g(msk + ((size_t)(rp * 258 + s + 1)) * 32 + blk, 1u);
    }
    if (s <= 254) {  // prefetch next xg0 (all waves)
      const float* q = xg0 + (size_t)(s + 1) * 49152 + eb * 1536 + jg;
      gxr = ldf_p(q); gxz = ldf_p(q + 512); gxn = ldf_p(q + 1024);
    }
  }
}

// ---------------- in-place log_softmax over rows of 10000 ----------------
__global__ __launch_bounds__(256) void k_logsoftmax(float* __restrict__ out) {
  const int row = blockIdx.x, tid = threadIdx.x;
  float* p = out + (size_t)row * 10000;
  const int n_own = (tid < 16) ? 40 : 39;
  float v[40];
  float mx = -3.4e38f;
#pragma unroll
  for (int i = 0; i < 40; ++i)
    if (i < n_own) { v[i] = p[i * 256 + tid]; mx = fmaxf(mx, v[i]); }
  for (int o = 32; o; o >>= 1) mx = fmaxf(mx, __shfl_xor(mx, o));
  __shared__ float sm[4], ss[4];
  if ((tid & 63) == 0) sm[tid >> 6] = mx;
  __syncthreads();
  mx = fmaxf(fmaxf(sm[0], sm[1]), fmaxf(sm[2], sm[3]));
  float s = 0.f;
#pragma unroll
  for (int i = 0; i < 40; ++i)
    if (i < n_own) s += __expf(v[i] - mx);
  for (int o = 32; o; o >>= 1) s += __shfl_xor(s, o);
  if ((tid & 63) == 0) ss[tid >> 6] = s;
  __syncthreads();
  s = ss[0] + ss[1] + ss[2] + ss[3];
  float lse = mx + __logf(s);
#pragma unroll
  for (int i = 0; i < 40; ++i)
    if (i < n_own) p[i * 256 + tid] = v[i] - lse;
}

extern "C" void kernel_launch(void* const* d_in, const int* in_sizes, int n_in,
                              void* d_out, int out_size, void* d_ws, size_t ws_size,
                              hipStream_t stream) {
  (void)in_sizes; (void)n_in; (void)out_size;
  const int*   loc    = (const int*)  d_in[0];
  const float* times  = (const float*)d_in[1];
  const int*   labels = (const int*)  d_in[2];
  const float* emb    = (const float*)d_in[3];
  const float* traj   = (const float*)d_in[4];
  const float* w_ih0  = (const float*)d_in[5];
  const float* w_hh0  = (const float*)d_in[6];
  const float* b_ih0  = (const float*)d_in[7];
  const float* b_hh0  = (const float*)d_in[8];
  const float* w_ih1  = (const float*)d_in[9];
  const float* w_hh1  = (const float*)d_in[10];
  const float* b_ih1  = (const float*)d_in[11];
  const float* b_hh1  = (const float*)d_in[12];
  const float* fc_w   = (const float*)d_in[13];
  const float* fc_b   = (const float*)d_in[14];

  if (ws_size < 31500000) return;

  char* ws = (char*)d_ws;
  size_t off = 0;
  auto alloc = [&](size_t b) { size_t r = off; off += (b + 255) & ~(size_t)255; return r; };
  unsigned* msk  = (unsigned*)(ws + alloc(4 * 258 * 32 * 4));
  u16*   h0x   = (u16*)  (ws + alloc(2 * 32 * 512 * 2));
  u16*   h1x   = (u16*)  (ws + alloc(2 * 32 * 512 * 2));
  u16*   x0    = (u16*)  (ws + alloc((size_t)8192 * 288 * 2));
  u16*   wih0b = (u16*)  (ws + alloc((size_t)1536 * 288 * 2));
  u16*   whh0b = (u16*)  (ws + alloc((size_t)1536 * 512 * 2));
  u16*   wih1b = (u16*)  (ws + alloc((size_t)1536 * 512 * 2));
  u16*   whh1b = (u16*)  (ws + alloc((size_t)1536 * 512 * 2));
  u16*   fcwb  = (u16*)  (ws + alloc((size_t)10112 * 512 * 2));
  u16*   h1seq = (u16*)  (ws + alloc((size_t)8192 * 512 * 2));

  float* outp = (float*)d_out;
  float* xg0  = outp;                 // [8192][1536] scratch in d_out (dead until FC)
  float* tptr = outp + 81920000;      // time [8192]

  hipFuncSetAttribute((const void*)k_scan7, hipFuncAttributeMaxDynamicSharedMemorySize, 162816);

  hipMemsetAsync(msk, 0, 4 * 258 * 32 * 4, stream);
  k_maskinit<<<1, 128, 0, stream>>>(msk);
  k_castpad<<<1024, 256, 0, stream>>>(w_ih0, wih0b, 1536, 257, 1536, 288);
  k_castpad<<<1024, 256, 0, stream>>>(w_hh0, whh0b, 1536, 512, 1536, 512);
  k_castpad<<<1024, 256, 0, stream>>>(w_ih1, wih1b, 1536, 512, 1536, 512);
  k_castpad<<<1024, 256, 0, stream>>>(w_hh1, whh1b, 1536, 512, 1536, 512);
  k_castpad<<<1024, 256, 0, stream>>>(fc_w, fcwb, 10001, 512, 10112, 512);
  k_embed<<<2048, 256, 0, stream>>>(loc, times, emb, x0);
  k_gemm<0><<<dim3(12, 64), 256, 0, stream>>>(x0, wih0b, b_ih0, xg0, 1536, 288, nullptr);
  k_hinit<<<64, 256, 0, stream>>>(traj, labels, h0x + 16384, 0);  // h0(-1) -> parity 1
  k_hinit<<<64, 256, 0, stream>>>(traj, labels, h1x + 16384, 1);  // h1(-1) -> parity 1
  k_scan7<<<32, 512, 162816, stream>>>(xg0, whh0b, b_hh0, wih1b, b_ih1, whh1b, b_hh1,
                                       traj, labels, h0x, h1x, h1seq, msk);
  k_gemm<1><<<dim3(79, 64), 256, 0, stream>>>(h1seq, fcwb, fc_b, outp, 10112, 512, tptr);
  k_logsoftmax<<<8192, 256, 0, stream>>>(outp);
}

// Round 11
// 1782.463 us; speedup vs baseline: 1.4808x; 1.0999x over previous
//
#include <hip/hip_runtime.h>

typedef unsigned short u16;
typedef __bf16 bf16x8 __attribute__((ext_vector_type(8)));
typedef float f32x4 __attribute__((ext_vector_type(4)));

#define DEVI __device__ __forceinline__

DEVI u16 f2b(float f) {
  union { float f; unsigned u; } c; c.f = f;
  unsigned r = c.u + 0x7FFFu + ((c.u >> 16) & 1u);
  return (u16)(r >> 16);
}

DEVI float sigm(float x) { return 1.f / (1.f + __expf(-x)); }
DEVI float tanhfast(float x) {
  x = fminf(fmaxf(x, -15.f), 15.f);
  float e = __expf(2.f * x);
  return (e - 1.f) / (e + 1.f);
}

DEVI void async16(const void* g, void* l) {
  __builtin_amdgcn_global_load_lds((const __attribute__((address_space(1))) void*)g,
                                   (__attribute__((address_space(3))) void*)l, 16, 0, 0);
}

// LLC-bypass 16B load (sc0 sc1). Caller must vmcnt(0)+sched_barrier before use.
DEVI f32x4 ld16cc(const u16* p) {
  f32x4 r;
  asm volatile("global_load_dwordx4 %0, %1, off sc0 sc1" : "=v"(r) : "v"(p) : "memory");
  return r;
}

#define VM0 asm volatile("s_waitcnt vmcnt(0)" ::: "memory")
#define SBAR __builtin_amdgcn_sched_barrier(0)

// ---------------- cast / pad fp32 -> bf16 ----------------
__global__ __launch_bounds__(256) void k_castpad(const float* __restrict__ src, u16* __restrict__ dst,
                                                 int srows, int scols, int drows, int dcols) {
  size_t n = (size_t)drows * dcols;
  for (size_t i = blockIdx.x * 256 + threadIdx.x; i < n; i += (size_t)gridDim.x * 256) {
    int r = (int)(i / dcols), c = (int)(i % dcols);
    float v = (r < srows && c < scols) ? src[(size_t)r * scols + c] : 0.f;
    dst[i] = f2b(v);
  }
}

// ---------------- embedding + time concat -> x0 bf16 [8192][288] ----------------
__global__ __launch_bounds__(256) void k_embed(const int* __restrict__ loc, const float* __restrict__ times,
                                               const float* __restrict__ emb, u16* __restrict__ x0) {
  int m = blockIdx.x * 4 + (threadIdx.x >> 6);  // m = t*32 + b
  int s = threadIdx.x & 63;
  int b = m & 31, t = m >> 5;
  int li = loc[b * 256 + t];
  const float4* er = (const float4*)(emb + (size_t)li * 256);
  u16* xr = x0 + (size_t)m * 288;
  float4 v = er[s];
  ushort4 u;
  u.x = f2b(v.x); u.y = f2b(v.y); u.z = f2b(v.z); u.w = f2b(v.w);
  *(ushort4*)(xr + s * 4) = u;
  if (s == 0) xr[256] = f2b(times[b * 256 + t]);
  else if (s <= 31) xr[256 + s] = 0;
}

// ---------------- init h seed (bf16) from traj_emb[labels] ----------------
__global__ __launch_bounds__(256) void k_hinit(const float* __restrict__ traj, const int* __restrict__ labels,
                                               u16* __restrict__ dst, int layer) {
  int idx = blockIdx.x * 256 + threadIdx.x;
  if (idx < 16384) {
    int fidx = layer * 16384 + idx;
    dst[idx] = f2b(traj[(size_t)labels[fidx >> 10] * 1024 + (fidx & 1023)]);
  }
}

// ---------------- preset tag0[rep][0][w] = 1 ----------------
__global__ __launch_bounds__(128) void k_taginit(unsigned* __restrict__ tag0) {
  int t = threadIdx.x;           // t = rep*32 + w
  tag0[(t >> 5) * 259 * 32 + (t & 31)] = 1u;
}

// ---------------- bf16 MFMA GEMM: C[M,N] = A[M,K] * Bw[N,K]^T (+bias) ----------------
template <int MODE>
__global__ __launch_bounds__(256) void k_gemm(const u16* __restrict__ A, const u16* __restrict__ Bw,
                                              const float* __restrict__ bias, float* __restrict__ C,
                                              int N, int K, float* __restrict__ tptr) {
  __shared__ __align__(16) u16 As[128 * 32];
  __shared__ __align__(16) u16 Bs[128 * 32];
  const int tid = threadIdx.x;
  const int lane = tid & 63, wid = tid >> 6;
  const int tn = blockIdx.x, tm = blockIdx.y;
  const int wm = wid >> 1, wn = wid & 1;

  f32x4 acc[4][4] = {};

  const int r0 = tid >> 2;
  const int cb0 = (tid * 16) & 63;

  for (int k0 = 0; k0 < K; k0 += 32) {
    __syncthreads();
#pragma unroll
    for (int p = 0; p < 2; ++p) {
      int row = r0 + p * 64;
      const u16* ga = A + (size_t)(tm * 128 + row) * K + k0 + (cb0 >> 1);
      async16(ga, (void*)(As + wid * 512 + p * 2048));
      const u16* gb = Bw + (size_t)(tn * 128 + row) * K + k0 + (cb0 >> 1);
      async16(gb, (void*)(Bs + wid * 512 + p * 2048));
    }
    asm volatile("s_waitcnt vmcnt(0)" ::: "memory");
    __syncthreads();
    bf16x8 af[4], bf[4];
#pragma unroll
    for (int i = 0; i < 4; ++i) {
      af[i] = *reinterpret_cast<const bf16x8*>(As + (wm * 64 + i * 16 + (lane & 15)) * 32 + ((lane >> 4) * 8));
      bf[i] = *reinterpret_cast<const bf16x8*>(Bs + (wn * 64 + i * 16 + (lane & 15)) * 32 + ((lane >> 4) * 8));
    }
#pragma unroll
    for (int i = 0; i < 4; ++i)
#pragma unroll
      for (int j = 0; j < 4; ++j)
        acc[i][j] = __builtin_amdgcn_mfma_f32_16x16x32_bf16(af[i], bf[j], acc[i][j], 0, 0, 0);
  }

  const int row0 = tm * 128 + wm * 64;
  const int col0 = tn * 128 + wn * 64;
#pragma unroll
  for (int i = 0; i < 4; ++i)
#pragma unroll
    for (int j = 0; j < 4; ++j)
#pragma unroll
      for (int r = 0; r < 4; ++r) {
        int row = row0 + i * 16 + ((lane >> 4) * 4) + r;
        int col = col0 + j * 16 + (lane & 15);
        float v = acc[i][j][r];
        if (MODE == 0) {
          C[(size_t)row * N + col] = v + bias[col];
        } else {
          int orow = ((row & 31) << 8) + (row >> 5);  // b*256 + t
          if (col < 10000) C[(size_t)orow * 10000 + col] = v + bias[col];
          else if (col == 10000) tptr[orow] = sigm(v + bias[col]);
        }
      }
}

// ---------------- fused persistent 2-layer GRU scan, tag-flag sync (r3 base) ----------------
// EXACT r3 structure (passed, 1385us): 64 blocks, role0 (blk 0-31) = h0 + X1
// production into global x1x ring(8); role1 (blk 32-63) = h1 + h1seq, lag 2.
// Sync: per-writer tag dwords, 4 replicas, ballot polls; x1x backpressure
// slack 6 folded into role0's poll. SINGLE CHANGE vs r3: weights (whh, wih1)
// moved from VGPRs (r3 spilled: VGPR_Count=100 < 128-reg resident set) into
// dynamic LDS, XOR-swizzled, read per-MFMA (r6-r8-proven machinery).
// LDS: [0,48K) whh0|whh1; [48K,96K) wih1 (role0); [96K,102K) smD.
__global__ __launch_bounds__(512)
void k_scan9(const float* __restrict__ xg0,
             const u16* __restrict__ whh0, const float* __restrict__ bhh0,
             const u16* __restrict__ wih1, const float* __restrict__ bih1,
             const u16* __restrict__ whh1, const float* __restrict__ bhh1,
             const float* __restrict__ traj, const int* __restrict__ labels,
             u16* __restrict__ h0x, u16* __restrict__ h1x, float* __restrict__ x1x,
             u16* __restrict__ h1seq, unsigned* __restrict__ tag0, unsigned* __restrict__ tag1)
{
  extern __shared__ __align__(16) char dynlds[];
  float* smD = (float*)(dynlds + 98304);  // [2 mt][3 nt][16][16] f32 = 6144B

  const int tid = threadIdx.x, bid = blockIdx.x;
  const int role = bid >> 5, blk = bid & 31;
  const int lane = tid & 63, wid = tid >> 6;
  const int rep = bid & 3;

  const int eb = tid >> 4, ejj = tid & 15;
  const int jg = (blk << 4) + ejj;

  const float* bhh = (role == 0) ? bhh0 : bhh1;
  int fidx = (role == 1 ? 16384 : 0) + eb * 512 + jg;
  float h_own = traj[(size_t)labels[fidx >> 10] * 1024 + (fidx & 1023)];
  const float bh_r = bhh[jg], bh_z = bhh[512 + jg], bh_n = bhh[1024 + jg];

  const int mt = (wid < 6) ? wid / 3 : 0, nt = (wid < 6) ? wid % 3 : 0;
  float bX = 0.f;
  if (wid < 6 && role == 0) bX = bih1[nt * 512 + (blk << 4) + (lane & 15)];

  // ---- LDS weight preload (swizzled, r6-proven): whh -> 0; wih1 -> 48K (role0) ----
  {
    const u16* wh = (role == 0) ? whh0 : whh1;
    for (int c = tid; c < 3072; c += 512) {
      int row = c >> 6, o16 = c & 63;
      int grow = (row >> 4) * 512 + (blk << 4) + (row & 15);
      *(float4*)(dynlds + (row << 10) + ((o16 * 16) ^ ((row & 7) << 4))) =
          *(const float4*)(wh + (size_t)grow * 512 + o16 * 8);
    }
    if (role == 0) {
      for (int c = tid; c < 3072; c += 512) {
        int row = c >> 6, o16 = c & 63;
        int grow = (row >> 4) * 512 + (blk << 4) + (row & 15);
        *(float4*)(dynlds + 49152 + (row << 10) + ((o16 * 16) ^ ((row & 7) << 4))) =
            *(const float4*)(wih1 + (size_t)grow * 512 + o16 * 8);
      }
    }
  }
  __syncthreads();

  const u16* hsrc = (role == 0) ? h0x : h1x;
  u16* hdst = (role == 0) ? h0x : h1x;
  unsigned* mytag = (role == 0) ? tag0 : tag1;

  for (int s = 0; s < 258; ++s) {
    if (role == 0 && s == 257) break;
    const int rp = (s + 1) & 1, wp = s & 1;

    if (role == 0) {
      // gate loads for xg(s) — plain cached (compiler inserts waitcnt before use)
      float gxr = 0.f, gxz = 0.f, gxn = 0.f;
      if (s < 256) {
        const float* q = xg0 + (size_t)s * 49152 + eb * 1536 + jg;
        gxr = q[0]; gxz = q[512]; gxn = q[1024];
      }
      // poll: lanes<32 = h0(s-1) ready; lanes>=32 = x1x backpressure (slack 6)
      {
        const unsigned* tp;
        if (lane < 32)       tp = tag0 + ((size_t)(rep * 259 + s)) * 32 + lane;
        else if (s >= 9)     tp = tag1 + ((size_t)(rep * 259 + (s - 6))) * 32 + (lane - 32);
        else                 tp = tag0 + ((size_t)(rep * 259 + s)) * 32 + (lane - 32);
        while (__ballot(__hip_atomic_load(tp, __ATOMIC_RELAXED, __HIP_MEMORY_SCOPE_AGENT) != 0u) != ~0ull) {}
      }
      if (wid < 6) {
        const u16* hs = hsrc + (rp << 14) + ((mt * 16 + (lane & 15)) << 9) + ((lane >> 4) * 8);
        f32x4 afr[16];
#pragma unroll
        for (int ks = 0; ks < 16; ++ks) afr[ks] = ld16cc(hs + ks * 32);
        VM0; SBAR;
        const int col = lane & 15, rb = (lane >> 4) << 2;
        const int cb = (lane >> 4) << 4;
        const int swz = (col & 7) << 4;
        const int rowoff = (nt * 16 + col) << 10;
        if (s < 256) {  // H0 = w_hh0 @ h0(s-1)
          f32x4 a0 = {0.f, 0.f, 0.f, 0.f}, a1 = {0.f, 0.f, 0.f, 0.f};
#pragma unroll
          for (int ks = 0; ks < 8; ++ks) {
            bf16x8 w0 = *(const bf16x8*)(dynlds + rowoff + (((2 * ks) * 64 + cb) ^ swz));
            bf16x8 w1 = *(const bf16x8*)(dynlds + rowoff + (((2 * ks + 1) * 64 + cb) ^ swz));
            a0 = __builtin_amdgcn_mfma_f32_16x16x32_bf16(__builtin_bit_cast(bf16x8, afr[2 * ks]),     w0, a0, 0, 0, 0);
            a1 = __builtin_amdgcn_mfma_f32_16x16x32_bf16(__builtin_bit_cast(bf16x8, afr[2 * ks + 1]), w1, a1, 0, 0, 0);
          }
#pragma unroll
          for (int r = 0; r < 4; ++r)
            smD[(mt * 3 + nt) * 256 + (rb + r) * 16 + col] = a0[r] + a1[r];
        }
        if (s >= 1) {  // X1(s-1) = w_ih1 @ h0(s-1) -> global ring
          f32x4 c0 = {0.f, 0.f, 0.f, 0.f}, c1 = {0.f, 0.f, 0.f, 0.f};
#pragma unroll
          for (int ks = 0; ks < 8; ++ks) {
            bf16x8 w0 = *(const bf16x8*)(dynlds + 49152 + rowoff + (((2 * ks) * 64 + cb) ^ swz));
            bf16x8 w1 = *(const bf16x8*)(dynlds + 49152 + rowoff + (((2 * ks + 1) * 64 + cb) ^ swz));
            c0 = __builtin_amdgcn_mfma_f32_16x16x32_bf16(__builtin_bit_cast(bf16x8, afr[2 * ks]),     w0, c0, 0, 0, 0);
            c1 = __builtin_amdgcn_mfma_f32_16x16x32_bf16(__builtin_bit_cast(bf16x8, afr[2 * ks + 1]), w1, c1, 0, 0, 0);
          }
          float* xp = x1x + (size_t)((s - 1) & 7) * 49152;
#pragma unroll
          for (int r = 0; r < 4; ++r) {
            int ebr = mt * 16 + rb + r;
            __hip_atomic_store(xp + ((ebr * 3 + nt) << 9) + (blk << 4) + col,
                               c0[r] + c1[r] + bX, __ATOMIC_RELAXED, __HIP_MEMORY_SCOPE_AGENT);
          }
        }
      }
      __syncthreads();
      if (s < 256) {
        float Dr = smD[((eb >> 4) * 3 + 0) * 256 + (eb & 15) * 16 + ejj] + bh_r;
        float Dz = smD[((eb >> 4) * 3 + 1) * 256 + (eb & 15) * 16 + ejj] + bh_z;
        float Dn = smD[((eb >> 4) * 3 + 2) * 256 + (eb & 15) * 16 + ejj] + bh_n;
        float r = sigm(gxr + Dr);
        float z = sigm(gxz + Dz);
        float n = tanhfast(gxn + r * Dn);
        h_own = (1.f - z) * n + z * h_own;
        unsigned hv = f2b(h_own);
        unsigned oth = __shfl_xor(hv, 1);
        if (!(ejj & 1))
          __hip_atomic_store((unsigned*)(hdst + (wp << 14)) + (((eb << 9) + jg) >> 1),
                             hv | (oth << 16), __ATOMIC_RELAXED, __HIP_MEMORY_SCOPE_AGENT);
      }
    } else {  // role 1: t = s-2
      if (s >= 2) {
        {
          const unsigned* tp = (lane < 32)
              ? tag0 + ((size_t)(rep * 259 + s)) * 32 + lane
              : tag1 + ((size_t)(rep * 259 + s)) * 32 + (lane - 32);
          while (__ballot(__hip_atomic_load(tp, __ATOMIC_RELAXED, __HIP_MEMORY_SCOPE_AGENT) != 0u) != ~0ull) {}
        }
        float* xp = x1x + (size_t)((s - 2) & 7) * 49152 + ((eb * 3) << 9) + jg;
        float gxr = __hip_atomic_load(xp,        __ATOMIC_RELAXED, __HIP_MEMORY_SCOPE_AGENT);
        float gxz = __hip_atomic_load(xp + 512,  __ATOMIC_RELAXED, __HIP_MEMORY_SCOPE_AGENT);
        float gxn = __hip_atomic_load(xp + 1024, __ATOMIC_RELAXED, __HIP_MEMORY_SCOPE_AGENT);
        if (wid < 6) {
          const u16* hs = hsrc + (rp << 14) + ((mt * 16 + (lane & 15)) << 9) + ((lane >> 4) * 8);
          f32x4 afr[16];
#pragma unroll
          for (int ks = 0; ks < 16; ++ks) afr[ks] = ld16cc(hs + ks * 32);
          VM0; SBAR;
          const int col = lane & 15, rb = (lane >> 4) << 2;
          const int cb = (lane >> 4) << 4;
          const int swz = (col & 7) << 4;
          const int rowoff = (nt * 16 + col) << 10;
          f32x4 a0 = {0.f, 0.f, 0.f, 0.f}, a1 = {0.f, 0.f, 0.f, 0.f};
#pragma unroll
          for (int ks = 0; ks < 8; ++ks) {
            bf16x8 w0 = *(const bf16x8*)(dynlds + rowoff + (((2 * ks) * 64 + cb) ^ swz));
            bf16x8 w1 = *(const bf16x8*)(dynlds + rowoff + (((2 * ks + 1) * 64 + cb) ^ swz));
            a0 = __builtin_amdgcn_mfma_f32_16x16x32_bf16(__builtin_bit_cast(bf16x8, afr[2 * ks]),     w0, a0, 0, 0, 0);
            a1 = __builtin_amdgcn_mfma_f32_16x16x32_bf16(__builtin_bit_cast(bf16x8, afr[2 * ks + 1]), w1, a1, 0, 0, 0);
          }
#pragma unroll
          for (int r = 0; r < 4; ++r)
            smD[(mt * 3 + nt) * 256 + (rb + r) * 16 + col] = a0[r] + a1[r];
        }
        __syncthreads();
        float Dr = smD[((eb >> 4) * 3 + 0) * 256 + (eb & 15) * 16 + ejj] + bh_r;
        float Dz = smD[((eb >> 4) * 3 + 1) * 256 + (eb & 15) * 16 + ejj] + bh_z;
        float Dn = smD[((eb >> 4) * 3 + 2) * 256 + (eb & 15) * 16 + ejj] + bh_n;
        float r = sigm(gxr + Dr);
        float z = sigm(gxz + Dz);
        float n = tanhfast(gxn + r * Dn);
        h_own = (1.f - z) * n + z * h_own;
        unsigned hv = f2b(h_own);
        unsigned oth = __shfl_xor(hv, 1);
        if (!(ejj & 1))
          __hip_atomic_store((unsigned*)(hdst + (wp << 14)) + (((eb << 9) + jg) >> 1),
                             hv | (oth << 16), __ATOMIC_RELAXED, __HIP_MEMORY_SCOPE_AGENT);
        h1seq[((size_t)((s - 2) * 32 + eb) << 9) + jg] = f2b(fmaxf(h_own, 0.f));
      }
    }
    // drain own publishes, then signal
    asm volatile("s_waitcnt vmcnt(0)" ::: "memory");
    __syncthreads();
    if (tid == 0 && s < 257) {
#pragma unroll
      for (int r = 0; r < 4; ++r)
        __hip_atomic_store(mytag + ((size_t)(r * 259 + s + 1)) * 32 + blk, 1u,
                           __ATOMIC_RELAXED, __HIP_MEMORY_SCOPE_AGENT);
    }
  }
}

// ---------------- in-place log_softmax over rows of 10000 ----------------
__global__ __launch_bounds__(256) void k_logsoftmax(float* __restrict__ out) {
  const int row = blockIdx.x, tid = threadIdx.x;
  float* p = out + (size_t)row * 10000;
  const int n_own = (tid < 16) ? 40 : 39;
  float v[40];
  float mx = -3.4e38f;
#pragma unroll
  for (int i = 0; i < 40; ++i)
    if (i < n_own) { v[i] = p[i * 256 + tid]; mx = fmaxf(mx, v[i]); }
  for (int o = 32; o; o >>= 1) mx = fmaxf(mx, __shfl_xor(mx, o));
  __shared__ float sm[4], ss[4];
  if ((tid & 63) == 0) sm[tid >> 6] = mx;
  __syncthreads();
  mx = fmaxf(fmaxf(sm[0], sm[1]), fmaxf(sm[2], sm[3]));
  float s = 0.f;
#pragma unroll
  for (int i = 0; i < 40; ++i)
    if (i < n_own) s += __expf(v[i] - mx);
  for (int o = 32; o; o >>= 1) s += __shfl_xor(s, o);
  if ((tid & 63) == 0) ss[tid >> 6] = s;
  __syncthreads();
  s = ss[0] + ss[1] + ss[2] + ss[3];
  float lse = mx + __logf(s);
#pragma unroll
  for (int i = 0; i < 40; ++i)
    if (i < n_own) p[i * 256 + tid] = v[i] - lse;
}

extern "C" void kernel_launch(void* const* d_in, const int* in_sizes, int n_in,
                              void* d_out, int out_size, void* d_ws, size_t ws_size,
                              hipStream_t stream) {
  (void)in_sizes; (void)n_in; (void)out_size;
  const int*   loc    = (const int*)  d_in[0];
  const float* times  = (const float*)d_in[1];
  const int*   labels = (const int*)  d_in[2];
  const float* emb    = (const float*)d_in[3];
  const float* traj   = (const float*)d_in[4];
  const float* w_ih0  = (const float*)d_in[5];
  const float* w_hh0  = (const float*)d_in[6];
  const float* b_ih0  = (const float*)d_in[7];
  const float* b_hh0  = (const float*)d_in[8];
  const float* w_ih1  = (const float*)d_in[9];
  const float* w_hh1  = (const float*)d_in[10];
  const float* b_ih1  = (const float*)d_in[11];
  const float* b_hh1  = (const float*)d_in[12];
  const float* fc_w   = (const float*)d_in[13];
  const float* fc_b   = (const float*)d_in[14];

  if (ws_size < 32000000) return;

  char* ws = (char*)d_ws;
  size_t off = 0;
  auto alloc = [&](size_t b) { size_t r = off; off += (b + 255) & ~(size_t)255; return r; };
  unsigned* tag0 = (unsigned*)(ws + alloc(4 * 259 * 32 * 4));   // 132608 B (mult of 256)
  unsigned* tag1 = (unsigned*)(ws + alloc(4 * 259 * 32 * 4));   // contiguous with tag0
  u16*   h0x   = (u16*)  (ws + alloc(2 * 32 * 512 * 2));
  u16*   h1x   = (u16*)  (ws + alloc(2 * 32 * 512 * 2));
  float* x1x   = (float*)(ws + alloc((size_t)8 * 32 * 3 * 512 * 4));
  u16*   x0    = (u16*)  (ws + alloc((size_t)8192 * 288 * 2));
  u16*   wih0b = (u16*)  (ws + alloc((size_t)1536 * 288 * 2));
  u16*   whh0b = (u16*)  (ws + alloc((size_t)1536 * 512 * 2));
  u16*   wih1b = (u16*)  (ws + alloc((size_t)1536 * 512 * 2));
  u16*   whh1b = (u16*)  (ws + alloc((size_t)1536 * 512 * 2));
  u16*   fcwb  = (u16*)  (ws + alloc((size_t)10112 * 512 * 2));
  u16*   h1seq = (u16*)  (ws + alloc((size_t)8192 * 512 * 2));

  float* outp = (float*)d_out;
  float* xg0  = outp;                 // [8192][1536] scratch in d_out (dead until FC)
  float* tptr = outp + 81920000;      // time [8192]

  hipFuncSetAttribute((const void*)k_scan9, hipFuncAttributeMaxDynamicSharedMemorySize, 104448);

  hipMemsetAsync(tag0, 0, 2 * 4 * 259 * 32 * 4, stream);  // tag0+tag1 contiguous
  k_taginit<<<1, 128, 0, stream>>>(tag0);
  k_castpad<<<1024, 256, 0, stream>>>(w_ih0, wih0b, 1536, 257, 1536, 288);
  k_castpad<<<1024, 256, 0, stream>>>(w_hh0, whh0b, 1536, 512, 1536, 512);
  k_castpad<<<1024, 256, 0, stream>>>(w_ih1, wih1b, 1536, 512, 1536, 512);
  k_castpad<<<1024, 256, 0, stream>>>(w_hh1, whh1b, 1536, 512, 1536, 512);
  k_castpad<<<1024, 256, 0, stream>>>(fc_w, fcwb, 10001, 512, 10112, 512);
  k_embed<<<2048, 256, 0, stream>>>(loc, times, emb, x0);
  k_gemm<0><<<dim3(12, 64), 256, 0, stream>>>(x0, wih0b, b_ih0, xg0, 1536, 288, nullptr);
  k_hinit<<<64, 256, 0, stream>>>(traj, labels, h0x + 16384, 0);  // h0(-1) -> parity 1
  k_hinit<<<64, 256, 0, stream>>>(traj, labels, h1x + 16384, 1);  // h1(-1) -> parity 1
  k_scan9<<<64, 512, 104448, stream>>>(xg0, whh0b, b_hh0, wih1b, b_ih1, whh1b, b_hh1,
                                       traj, labels, h0x, h1x, x1x, h1seq, tag0, tag1);
  k_gemm<1><<<dim3(79, 64), 256, 0, stream>>>(h1seq, fcwb, fc_b, outp, 10112, 512, tptr);
  k_logsoftmax<<<8192, 256, 0, stream>>>(outp);
}